// Round 6
// baseline (41968.906 us; speedup 1.0000x reference)
//
#include <hip/hip_runtime.h>

#define B_ 128
#define S_ 256
#define H_ 1024
#define V_ 512
#define T_ 128
#define G4 4096

typedef __attribute__((ext_vector_type(8))) short bf16x8;
typedef __attribute__((ext_vector_type(4))) float f32x4;

// ---------- helpers ----------
__device__ __forceinline__ float bf2f(unsigned short x) {
    unsigned int u = ((unsigned int)x) << 16;
    return __builtin_bit_cast(float, u);
}
__device__ __forceinline__ unsigned short f2b(float f) {
    unsigned int u = __builtin_bit_cast(unsigned int, f);
    u = u + 0x7fffu + ((u >> 16) & 1u);
    return (unsigned short)(u >> 16);
}
__device__ __forceinline__ float ftanh(float x) {
    float e = __expf(2.f * x);
    return 1.f - 2.f * __builtin_amdgcn_rcpf(e + 1.f);
}
__device__ __forceinline__ float fsigm(float x) {
    return __builtin_amdgcn_rcpf(1.f + __expf(-x));
}
__device__ __forceinline__ void gll16(const void* g, void* l) {
    __builtin_amdgcn_global_load_lds(
        (const __attribute__((address_space(1))) unsigned int*)g,
        (__attribute__((address_space(3))) unsigned int*)l, 16, 0, 0);
}

// ---------- small precompute kernels ----------
__global__ void f32_to_bf16_x4(const float4* __restrict__ in, ushort4* __restrict__ out, int n4) {
    int i = blockIdx.x * 256 + threadIdx.x;
    if (i < n4) {
        float4 v = in[i];
        ushort4 o;
        o.x = f2b(v.x); o.y = f2b(v.y); o.z = f2b(v.z); o.w = f2b(v.w);
        out[i] = o;
    }
}

__global__ void cvt_gather(const float* __restrict__ src, int src_ld, int coff,
                           unsigned short* __restrict__ dst, int perm) {
    int i = blockIdx.x * 256 + threadIdx.x;
    int r = i >> 8;
    int c = (i & 255) * 4;
    int sr = perm ? (((r & 3) << 10) + (r >> 2)) : r;
    float4 v = *reinterpret_cast<const float4*>(src + (size_t)sr * src_ld + coff + c);
    ushort4 o;
    o.x = f2b(v.x); o.y = f2b(v.y); o.z = f2b(v.z); o.w = f2b(v.w);
    *reinterpret_cast<ushort4*>(dst + (size_t)r * 1024 + c) = o;
}

__global__ void build_toks(const int* __restrict__ target, int* __restrict__ toks) {
    int idx = blockIdx.x * 256 + threadIdx.x;
    if (idx < T_ * B_) {
        int t = idx / B_, b = idx % B_;
        toks[idx] = (t == 0) ? 0 : target[b * T_ + t - 1];
    }
}

__global__ void build_bsum(const float* __restrict__ b_ih, const float* __restrict__ b_hh,
                           float* __restrict__ bsum) {
    int j = blockIdx.x * 256 + threadIdx.x;
    if (j < G4) {
        int pj = ((j & 3) << 10) + (j >> 2);
        bsum[j] = b_ih[pj] + b_hh[pj];
    }
}

// ---------- 64x64-tile bf16 MFMA GEMM (precompute only), BK=128, counted vmcnt ----------
template<int MODE>
__global__ __launch_bounds__(256) void gemm_mf(
    const unsigned short* __restrict__ A,
    const unsigned short* __restrict__ Bw,
    int K, int ldb, int ldc,
    float* __restrict__ C, unsigned short* __restrict__ Cb,
    const float* __restrict__ bias)
{
    __shared__ unsigned short As[2 * 8192];
    __shared__ unsigned short Bs[2 * 8192];
    const int tid = threadIdx.x;
    const int lane = tid & 63;
    const int wv = tid >> 6;
    const int m0 = blockIdx.x * 64;
    const int n0 = blockIdx.y * 64;

    const unsigned short* ga[4];
    const unsigned short* gb[4];
    #pragma unroll
    for (int j = 0; j < 4; ++j) {
        int ci = tid + 256 * j;
        int row = ci >> 4;
        int src = (ci & 15) ^ (row & 7);
        ga[j] = A + (size_t)(m0 + row) * K + src * 8;
        gb[j] = Bw + (size_t)(n0 + row) * ldb + src * 8;
    }

    f32x4 acc[2][2] = {};
    const int r0 = (wv >> 1) * 32;
    const int cq0 = (wv & 1) * 32;
    const int fr = lane & 15;
    const int kg = lane >> 4;

    auto stage = [&](int k0, int p) {
        #pragma unroll
        for (int j = 0; j < 4; ++j) {
            gll16(ga[j] + k0, As + p * 8192 + j * 2048 + wv * 512);
            gll16(gb[j] + k0, Bs + p * 8192 + j * 2048 + wv * 512);
        }
    };

    stage(0, 0);
    stage(128, 1);
    int p = 0;
    for (int k0 = 0; k0 < K; k0 += 128) {
        if (k0 + 128 < K) {
            asm volatile("s_waitcnt vmcnt(8)" ::: "memory");
        } else {
            asm volatile("s_waitcnt vmcnt(0)" ::: "memory");
        }
        __builtin_amdgcn_sched_barrier(0);
        __builtin_amdgcn_s_barrier();
        __builtin_amdgcn_sched_barrier(0);
        const unsigned short* Ab = As + p * 8192;
        const unsigned short* Bb = Bs + p * 8192;
        bf16x8 af[2][4], bfr[2][4];
        #pragma unroll
        for (int f = 0; f < 2; ++f)
            #pragma unroll
            for (int kh = 0; kh < 4; ++kh) {
                int ra = r0 + f * 16 + fr;
                af[f][kh] = *(const bf16x8*)&Ab[ra * 128 + (((kh * 4 + kg) ^ (ra & 7)) << 3)];
                int rb = cq0 + f * 16 + fr;
                bfr[f][kh] = *(const bf16x8*)&Bb[rb * 128 + (((kh * 4 + kg) ^ (rb & 7)) << 3)];
            }
        asm volatile("s_waitcnt lgkmcnt(0)" ::: "memory");
        __builtin_amdgcn_sched_barrier(0);
        __builtin_amdgcn_s_barrier();
        __builtin_amdgcn_sched_barrier(0);
        if (k0 + 256 < K) stage(k0 + 256, p);
        #pragma unroll
        for (int f = 0; f < 2; ++f)
            #pragma unroll
            for (int g = 0; g < 2; ++g)
                #pragma unroll
                for (int kh = 0; kh < 4; ++kh)
                    acc[f][g] = __builtin_amdgcn_mfma_f32_16x16x32_bf16(
                        af[f][kh], bfr[g][kh], acc[f][g], 0, 0, 0);
        p ^= 1;
    }

    const int erow = (lane >> 4) * 4;
    const int ecol = lane & 15;
    #pragma unroll
    for (int f = 0; f < 2; ++f) {
        #pragma unroll
        for (int g = 0; g < 2; ++g) {
            #pragma unroll
            for (int r = 0; r < 4; ++r) {
                int row = m0 + r0 + f * 16 + erow + r;
                int col = n0 + cq0 + g * 16 + ecol;
                float v = acc[f][g][r] + bias[col];
                if (MODE == 0) C[(size_t)row * ldc + col] = v;
                else Cb[(size_t)row * ldc + col] = f2b(v);
            }
        }
    }
}

// ---------- 64x32-tile bf16 MFMA GEMM, BK=128, counted vmcnt (per-step GEMMs) ----------
// MODE 0: C = v + bias[col]
// MODE 2: col<1024 -> Cq=q(+bias); col<5120 -> gates(+Pemb[tok]); else logits(t-1)+bias2
// MODE 4: gates-acc + fused LSTM pointwise epilogue
template<int MODE>
__global__ __launch_bounds__(256) void gemm_n32(
    const unsigned short* __restrict__ A,
    const unsigned short* __restrict__ Bw,
    int K, int ldb, int ldc,
    float* __restrict__ C, unsigned short* __restrict__ Cb,
    const float* __restrict__ bias,
    const float* __restrict__ Pemb,
    const int* __restrict__ toks,
    float* __restrict__ Cq,
    float* __restrict__ Lg,
    const float* __restrict__ bias2,
    int flag)
{
    __shared__ unsigned short As[2 * 8192];   // 64 x 128
    __shared__ unsigned short Bs[2 * 4096];   // 32 x 128
    const int tid = threadIdx.x;
    const int lane = tid & 63;
    const int wv = tid >> 6;
    const int m0 = blockIdx.x * 64;
    const int n0 = blockIdx.y * 32;

    const unsigned short* ga[4];
    const unsigned short* gb[2];
    #pragma unroll
    for (int j = 0; j < 4; ++j) {
        int ci = tid + 256 * j;
        int row = ci >> 4;
        int src = (ci & 15) ^ (row & 7);
        ga[j] = A + (size_t)(m0 + row) * K + src * 8;
    }
    #pragma unroll
    for (int j = 0; j < 2; ++j) {
        int ci = tid + 256 * j;
        int row = ci >> 4;
        int src = (ci & 15) ^ (row & 7);
        gb[j] = Bw + (size_t)(n0 + row) * ldb + src * 8;
    }

    f32x4 acc[2] = {};
    const int r0 = (wv >> 1) * 32;
    const int c0 = (wv & 1) * 16;
    const int fr = lane & 15;
    const int kg = lane >> 4;

    auto stage = [&](int k0, int p) {
        #pragma unroll
        for (int j = 0; j < 4; ++j)
            gll16(ga[j] + k0, As + p * 8192 + j * 2048 + wv * 512);
        #pragma unroll
        for (int j = 0; j < 2; ++j)
            gll16(gb[j] + k0, Bs + p * 4096 + j * 2048 + wv * 512);
    };

    stage(0, 0);
    stage(128, 1);
    int p = 0;
    for (int k0 = 0; k0 < K; k0 += 128) {
        if (k0 + 128 < K) {
            asm volatile("s_waitcnt vmcnt(6)" ::: "memory");
        } else {
            asm volatile("s_waitcnt vmcnt(0)" ::: "memory");
        }
        __builtin_amdgcn_sched_barrier(0);
        __builtin_amdgcn_s_barrier();
        __builtin_amdgcn_sched_barrier(0);
        const unsigned short* Ab = As + p * 8192;
        const unsigned short* Bb = Bs + p * 4096;
        bf16x8 af[2][4], bfr[4];
        #pragma unroll
        for (int kh = 0; kh < 4; ++kh) {
            #pragma unroll
            for (int f = 0; f < 2; ++f) {
                int ra = r0 + f * 16 + fr;
                af[f][kh] = *(const bf16x8*)&Ab[ra * 128 + (((kh * 4 + kg) ^ (ra & 7)) << 3)];
            }
            int rb = c0 + fr;
            bfr[kh] = *(const bf16x8*)&Bb[rb * 128 + (((kh * 4 + kg) ^ (rb & 7)) << 3)];
        }
        asm volatile("s_waitcnt lgkmcnt(0)" ::: "memory");
        __builtin_amdgcn_sched_barrier(0);
        __builtin_amdgcn_s_barrier();
        __builtin_amdgcn_sched_barrier(0);
        if (k0 + 256 < K) stage(k0 + 256, p);
        #pragma unroll
        for (int f = 0; f < 2; ++f)
            #pragma unroll
            for (int kh = 0; kh < 4; ++kh)
                acc[f] = __builtin_amdgcn_mfma_f32_16x16x32_bf16(
                    af[f][kh], bfr[kh], acc[f], 0, 0, 0);
        p ^= 1;
    }

    const int erow = (lane >> 4) * 4;
    const int ecol = lane & 15;

    if constexpr (MODE == 4) {
        __shared__ float Lt[64 * 32];
        __syncthreads();
        #pragma unroll
        for (int f = 0; f < 2; ++f)
            #pragma unroll
            for (int r = 0; r < 4; ++r)
                Lt[(r0 + f * 16 + erow + r) * 32 + c0 + ecol] = acc[f][r];
        __syncthreads();
        #pragma unroll
        for (int i = 0; i < 2; ++i) {
            int pi = tid + 256 * i;
            int r = pi >> 3, u = pi & 7;
            int b = m0 + r;
            int hh = (n0 >> 2) + u;
            f32x4 gv = *reinterpret_cast<const f32x4*>(&Lt[r * 32 + u * 4]);
            const float* gp = C + (size_t)b * G4 + n0 + u * 4;
            float iv = gv[0] + gp[0];
            float fv = gv[1] + gp[1];
            float gg = gv[2] + gp[2];
            float ov = gv[3] + gp[3];
            int ci = b * H_ + hh;
            float cn = fsigm(fv) * Cq[ci] + fsigm(iv) * ftanh(gg);
            float hn = fsigm(ov) * ftanh(cn);
            Cq[ci] = cn;
            Cb[ci] = f2b(hn);
            if (flag) Lg[ci] = hn;
        }
    } else {
        #pragma unroll
        for (int f = 0; f < 2; ++f) {
            #pragma unroll
            for (int r = 0; r < 4; ++r) {
                int row = m0 + r0 + f * 16 + erow + r;
                int col = n0 + c0 + ecol;
                float v = acc[f][r];
                if (MODE == 0) {
                    C[(size_t)row * ldc + col] = v + bias[col];
                } else {  // MODE 2
                    if (col < H_) {
                        Cq[(size_t)row * H_ + col] = v + bias[col];
                    } else if (col < 5120) {
                        int cg = col - H_;
                        C[(size_t)row * G4 + cg] = v + Pemb[(size_t)toks[row] * G4 + cg];
                    } else {
                        int cl = col - 5120;
                        Lg[(size_t)row * V_ + cl] = v + bias2[cl];
                    }
                }
            }
        }
    }
}

// ---------- fused attention: energies + partial ctx + last-block combine ----------
// grid (B,16) x 256. Last-arriving block per batch does softmax+ctx finalize.
__global__ __launch_bounds__(256) void attn_ec(
    const unsigned short* __restrict__ kp,   // [B*S, H] bf16
    const float* __restrict__ q,             // [B, H]
    const float* __restrict__ Va,            // [H]
    const unsigned short* __restrict__ encb, // [B*S, H] bf16
    float* __restrict__ es_g,                // [B, S]
    float* __restrict__ pctx,                // [B, 16, H]
    unsigned short* __restrict__ ctxb,       // [B, H] bf16
    float* __restrict__ attnOut,             // [B,T,S]
    const float* __restrict__ lg,            // [B, V] logits t-1
    float* __restrict__ lp,                  // [B,T,V]
    int* __restrict__ cnt,                   // [B] arrival counters (self-resetting)
    int t)
{
    const int b = blockIdx.x;
    const int sh = blockIdx.y;
    const int tid = threadIdx.x;
    const int lane = tid & 63;
    const int wv = tid >> 6;
    __shared__ float qs[H_];
    __shared__ float vas[H_];
    __shared__ float es[16], pe[16];
    __shared__ float redm[4], reds[4];
    __shared__ int flagS;

    *reinterpret_cast<float4*>(&qs[tid * 4]) =
        *reinterpret_cast<const float4*>(&q[(size_t)b * H_ + tid * 4]);
    *reinterpret_cast<float4*>(&vas[tid * 4]) =
        *reinterpret_cast<const float4*>(&Va[tid * 4]);

    // ---- log-softmax(t-1), sh==0 blocks only ----
    const bool doL = (t > 0) && (sh == 0);
    float a0 = doL ? lg[(size_t)b * V_ + tid] : -3.4e38f;
    float a1 = doL ? lg[(size_t)b * V_ + 256 + tid] : -3.4e38f;
    float mx = fmaxf(a0, a1);
    #pragma unroll
    for (int off = 32; off; off >>= 1) mx = fmaxf(mx, __shfl_xor(mx, off));
    if (lane == 0) redm[wv] = mx;
    __syncthreads();                         // also publishes qs/vas
    mx = fmaxf(fmaxf(redm[0], redm[1]), fmaxf(redm[2], redm[3]));
    float sm = doL ? (__expf(a0 - mx) + __expf(a1 - mx)) : 0.f;
    #pragma unroll
    for (int off = 32; off; off >>= 1) sm += __shfl_xor(sm, off);
    if (lane == 0) reds[wv] = sm;
    __syncthreads();
    if (doL) {
        sm = reds[0] + reds[1] + reds[2] + reds[3];
        float lse = mx + __logf(sm);
        size_t off = ((size_t)b * T_ + (t - 1)) * V_;
        lp[off + tid] = a0 - lse;
        lp[off + tid + 256] = a1 - lse;
    }

    // ---- energies: wave wv handles s_loc = wv*4 + 0..3 ----
    #pragma unroll
    for (int si = 0; si < 4; ++si) {
        int s_loc = wv * 4 + si;
        const unsigned short* kr = kp + (size_t)(b * S_ + sh * 16 + s_loc) * H_;
        float acc = 0.f;
        #pragma unroll
        for (int it = 0; it < 4; ++it) {
            int h4 = lane * 4 + it * 256;
            ushort4 u = *reinterpret_cast<const ushort4*>(kr + h4);
            acc += vas[h4 + 0] * ftanh(qs[h4 + 0] + bf2f(u.x));
            acc += vas[h4 + 1] * ftanh(qs[h4 + 1] + bf2f(u.y));
            acc += vas[h4 + 2] * ftanh(qs[h4 + 2] + bf2f(u.z));
            acc += vas[h4 + 3] * ftanh(qs[h4 + 3] + bf2f(u.w));
        }
        #pragma unroll
        for (int off = 32; off; off >>= 1) acc += __shfl_down(acc, off);
        if (lane == 0) {
            es[s_loc] = acc;
            es_g[(size_t)b * S_ + sh * 16 + s_loc] = acc;
        }
    }
    __syncthreads();

    // ---- partial context with local-max scaling ----
    float mb = es[0];
    #pragma unroll
    for (int i = 1; i < 16; ++i) mb = fmaxf(mb, es[i]);
    if (tid < 16) pe[tid] = __expf(es[tid] - mb);
    __syncthreads();
    const int c0 = tid * 4;
    {
        float ax = 0.f, ay = 0.f, az = 0.f, aw = 0.f;
        #pragma unroll
        for (int sl = 0; sl < 16; ++sl) {
            ushort4 u = *reinterpret_cast<const ushort4*>(
                &encb[(size_t)(b * S_ + sh * 16 + sl) * H_ + c0]);
            float w = pe[sl];
            ax += w * bf2f(u.x);
            ay += w * bf2f(u.y);
            az += w * bf2f(u.z);
            aw += w * bf2f(u.w);
        }
        float4 o4; o4.x = ax; o4.y = ay; o4.z = az; o4.w = aw;
        *reinterpret_cast<float4*>(&pctx[((size_t)b * 16 + sh) * H_ + c0]) = o4;
    }

    // ---- arrival; last block combines ----
    __threadfence();            // release our es_g/pctx writes (device scope)
    __syncthreads();
    if (tid == 0)
        flagS = __hip_atomic_fetch_add(&cnt[b], 1, __ATOMIC_ACQ_REL, __HIP_MEMORY_SCOPE_AGENT);
    __syncthreads();
    if (flagS != 15) return;
    __threadfence();            // acquire: see all 16 blocks' writes

    __shared__ float es2[S_], sc[16];
    __shared__ float redm2[4], reds2[4];
    float x = es_g[(size_t)b * S_ + tid];
    es2[tid] = x;
    float mx2 = x;
    #pragma unroll
    for (int off = 32; off; off >>= 1) mx2 = fmaxf(mx2, __shfl_xor(mx2, off));
    if (lane == 0) redm2[wv] = mx2;
    __syncthreads();
    mx2 = fmaxf(fmaxf(redm2[0], redm2[1]), fmaxf(redm2[2], redm2[3]));
    float ex = __expf(x - mx2);
    float sm2 = ex;
    #pragma unroll
    for (int off = 32; off; off >>= 1) sm2 += __shfl_xor(sm2, off);
    if (lane == 0) reds2[wv] = sm2;
    __syncthreads();
    sm2 = reds2[0] + reds2[1] + reds2[2] + reds2[3];
    float rZ = __builtin_amdgcn_rcpf(sm2);
    attnOut[((size_t)(b * T_ + t)) * S_ + tid] = ex * rZ;
    if (tid < 16) {
        float mb2 = es2[tid * 16];
        #pragma unroll
        for (int j = 1; j < 16; ++j) mb2 = fmaxf(mb2, es2[tid * 16 + j]);
        sc[tid] = __expf(mb2 - mx2);
    }
    __syncthreads();
    {
        float ax = 0.f, ay = 0.f, az = 0.f, aw = 0.f;
        #pragma unroll
        for (int blk = 0; blk < 16; ++blk) {
            float4 pv = *reinterpret_cast<const float4*>(
                &pctx[((size_t)b * 16 + blk) * H_ + c0]);
            float s = sc[blk];
            ax += s * pv.x; ay += s * pv.y; az += s * pv.z; aw += s * pv.w;
        }
        ushort4 o;
        o.x = f2b(ax * rZ); o.y = f2b(ay * rZ); o.z = f2b(az * rZ); o.w = f2b(aw * rZ);
        *reinterpret_cast<ushort4*>(&ctxb[(size_t)b * H_ + c0]) = o;
    }
    if (tid == 0) cnt[b] = 0;   // self-reset for next step / next replay
}

// ---------- standalone log-softmax (final step only) ----------
__global__ __launch_bounds__(256) void lsm_kernel(
    const float* __restrict__ lg, float* __restrict__ lp, int t)
{
    int b = blockIdx.x, tid = threadIdx.x;
    int lane = tid & 63, wv = tid >> 6;
    __shared__ float red[4];
    float a0 = lg[(size_t)b * V_ + tid];
    float a1 = lg[(size_t)b * V_ + 256 + tid];
    float mx = fmaxf(a0, a1);
    #pragma unroll
    for (int off = 32; off; off >>= 1) mx = fmaxf(mx, __shfl_xor(mx, off));
    if (lane == 0) red[wv] = mx;
    __syncthreads();
    mx = fmaxf(fmaxf(red[0], red[1]), fmaxf(red[2], red[3]));
    float sm = __expf(a0 - mx) + __expf(a1 - mx);
    #pragma unroll
    for (int off = 32; off; off >>= 1) sm += __shfl_xor(sm, off);
    __syncthreads();
    if (lane == 0) red[wv] = sm;
    __syncthreads();
    sm = red[0] + red[1] + red[2] + red[3];
    float lse = mx + __logf(sm);
    size_t off = ((size_t)b * T_ + t) * V_;
    lp[off + tid] = a0 - lse;
    lp[off + tid + 256] = a1 - lse;
}

// ---------- launch ----------
extern "C" void kernel_launch(void* const* d_in, const int* in_sizes, int n_in,
                              void* d_out, int out_size, void* d_ws, size_t ws_size,
                              hipStream_t stream) {
    const float* enc   = (const float*)d_in[0];
    const float* h0    = (const float*)d_in[1];
    const float* c0    = (const float*)d_in[2];
    const int*   targ  = (const int*)d_in[3];
    const float* emb   = (const float*)d_in[5];
    const float* Wa_w  = (const float*)d_in[6];
    const float* Wa_b  = (const float*)d_in[7];
    const float* Ua_w  = (const float*)d_in[8];
    const float* Ua_b  = (const float*)d_in[9];
    const float* Va_w  = (const float*)d_in[10];
    const float* W_ih  = (const float*)d_in[12];
    const float* W_hh  = (const float*)d_in[13];
    const float* b_ih  = (const float*)d_in[14];
    const float* b_hh  = (const float*)d_in[15];
    const float* out_w = (const float*)d_in[16];
    const float* out_b = (const float*)d_in[17];

    float* out  = (float*)d_out;
    float* lp   = out;                          // [B,T,V]
    float* hid  = out + (size_t)B_ * T_ * V_;   // [1,B,H]
    float* attn = hid + (size_t)B_ * H_;        // [B,T,S]

    char* w = (char*)d_ws;
    auto alloc = [&](size_t bytes) {
        char* p = w;
        w += (bytes + 255) & ~(size_t)255;
        return p;
    };
    const size_t NKP = (size_t)B_ * S_ * H_;
    unsigned short* kp     = (unsigned short*)alloc(NKP * 2);
    unsigned short* encb   = (unsigned short*)alloc(NKP * 2);
    unsigned short* Wcat_b = (unsigned short*)alloc((size_t)5632 * H_ * 2); // [Wa; W_hh(perm); out_w]
    unsigned short* Wih1_b = (unsigned short*)alloc((size_t)G4 * H_ * 2);   // W_ih[:, :H] perm
    unsigned short* Wih2_b = (unsigned short*)alloc((size_t)G4 * H_ * 2);   // W_ih[:, H:] perm
    unsigned short* Uaw_b  = (unsigned short*)alloc((size_t)H_ * H_ * 2);
    unsigned short* emb_b  = (unsigned short*)alloc((size_t)V_ * H_ * 2);
    unsigned short* hb     = (unsigned short*)alloc((size_t)B_ * H_ * 2);
    unsigned short* ctxb   = (unsigned short*)alloc((size_t)B_ * H_ * 2);
    float* Pemb  = (float*)alloc((size_t)V_ * G4 * 4);
    float* bsumP = (float*)alloc((size_t)G4 * 4);
    int*   toks  = (int*)alloc((size_t)T_ * B_ * 4);
    float* cbuf  = (float*)alloc((size_t)B_ * H_ * 4);
    float* qbuf  = (float*)alloc((size_t)B_ * H_ * 4);
    float* gates = (float*)alloc((size_t)B_ * G4 * 4);
    float* lgbuf = (float*)alloc((size_t)B_ * V_ * 4);
    float* es_g  = (float*)alloc((size_t)B_ * S_ * 4);
    float* pctx  = (float*)alloc((size_t)B_ * 16 * H_ * 4);
    int*   cnt   = (int*)alloc((size_t)B_ * 4);
    if ((size_t)(w - (char*)d_ws) > ws_size) return;

    auto cvt = [&](const float* src, unsigned short* dst, size_t n) {
        int n4 = (int)(n / 4);
        f32_to_bf16_x4<<<(n4 + 255) / 256, 256, 0, stream>>>((const float4*)src, (ushort4*)dst, n4);
    };

    // precompute
    hipMemsetAsync(cnt, 0, (size_t)B_ * 4, stream);
    cvt(enc, encb, NKP);
    cvt(Ua_w, Uaw_b, (size_t)H_ * H_);
    cvt(emb, emb_b, (size_t)V_ * H_);
    cvt(h0, hb, (size_t)B_ * H_);
    cvt_gather<<<1024, 256, 0, stream>>>(Wa_w, H_, 0, Wcat_b, 0);
    cvt_gather<<<4096, 256, 0, stream>>>(W_hh, H_, 0, Wcat_b + (size_t)1024 * H_, 1);
    cvt_gather<<<512, 256, 0, stream>>>(out_w, H_, 0, Wcat_b + (size_t)5120 * H_, 0);
    cvt_gather<<<4096, 256, 0, stream>>>(W_ih, 2 * H_, 0, Wih1_b, 1);
    cvt_gather<<<4096, 256, 0, stream>>>(W_ih, 2 * H_, H_, Wih2_b, 1);
    build_toks<<<(T_ * B_ + 255) / 256, 256, 0, stream>>>(targ, toks);
    build_bsum<<<(G4 + 255) / 256, 256, 0, stream>>>(b_ih, b_hh, bsumP);
    hipMemcpyAsync(cbuf, c0, (size_t)B_ * H_ * 4, hipMemcpyDeviceToDevice, stream);

    // keys_proj: kp = encb @ Ua_w^T + Ua_b (bf16 out)
    gemm_mf<1><<<dim3((B_ * S_) / 64, H_ / 64), 256, 0, stream>>>(
        encb, Uaw_b, H_, H_, H_, nullptr, kp, Ua_b);
    // Pemb (permuted): emb @ W_ih[:, :H](perm)^T + bsumP
    gemm_mf<0><<<dim3(V_ / 64, G4 / 64), 256, 0, stream>>>(
        emb_b, Wih1_b, H_, H_, G4, Pemb, nullptr, bsumP);

    // sequential decode: 3 launches per step
    for (int t = 0; t < T_; ++t) {
        gemm_n32<2><<<dim3(2, 176), 256, 0, stream>>>(
            hb, Wcat_b, H_, H_, 0, gates, nullptr, Wa_b,
            Pemb, toks + t * B_, qbuf, lgbuf, out_b, 0);
        attn_ec<<<dim3(B_, 16), 256, 0, stream>>>(
            kp, qbuf, Va_w, encb, es_g, pctx, ctxb, attn, lgbuf, lp, cnt, t);
        gemm_n32<4><<<dim3(2, 128), 256, 0, stream>>>(
            ctxb, Wih2_b, H_, H_, 0, gates, hb, nullptr,
            nullptr, nullptr, cbuf, hid, nullptr, t == T_ - 1);
    }
    // logits + lsm for final step
    gemm_n32<0><<<dim3(2, 16), 256, 0, stream>>>(
        hb, Wcat_b + (size_t)5120 * H_, H_, H_, V_, lgbuf, nullptr, out_b,
        nullptr, nullptr, nullptr, nullptr, nullptr, 0);
    lsm_kernel<<<B_, 256, 0, stream>>>(lgbuf, lp, T_ - 1);
}

// Round 7
// 6316.927 us; speedup vs baseline: 6.6439x; 6.6439x over previous
//
#include <hip/hip_runtime.h>

#define B_ 128
#define S_ 256
#define H_ 1024
#define V_ 512
#define T_ 128
#define G4 4096

typedef __attribute__((ext_vector_type(8))) short bf16x8;
typedef __attribute__((ext_vector_type(4))) float f32x4;

// ---------- helpers ----------
__device__ __forceinline__ float bf2f(unsigned short x) {
    unsigned int u = ((unsigned int)x) << 16;
    return __builtin_bit_cast(float, u);
}
__device__ __forceinline__ unsigned short f2b(float f) {
    unsigned int u = __builtin_bit_cast(unsigned int, f);
    u = u + 0x7fffu + ((u >> 16) & 1u);
    return (unsigned short)(u >> 16);
}
__device__ __forceinline__ float ftanh(float x) {
    float e = __expf(2.f * x);
    return 1.f - 2.f * __builtin_amdgcn_rcpf(e + 1.f);
}
__device__ __forceinline__ float fsigm(float x) {
    return __builtin_amdgcn_rcpf(1.f + __expf(-x));
}
__device__ __forceinline__ void gll16(const void* g, void* l) {
    __builtin_amdgcn_global_load_lds(
        (const __attribute__((address_space(1))) unsigned int*)g,
        (__attribute__((address_space(3))) unsigned int*)l, 16, 0, 0);
}

// ---------- small precompute kernels ----------
__global__ void f32_to_bf16_x4(const float4* __restrict__ in, ushort4* __restrict__ out, int n4) {
    int i = blockIdx.x * 256 + threadIdx.x;
    if (i < n4) {
        float4 v = in[i];
        ushort4 o;
        o.x = f2b(v.x); o.y = f2b(v.y); o.z = f2b(v.z); o.w = f2b(v.w);
        out[i] = o;
    }
}

__global__ void cvt_gather(const float* __restrict__ src, int src_ld, int coff,
                           unsigned short* __restrict__ dst, int perm) {
    int i = blockIdx.x * 256 + threadIdx.x;
    int r = i >> 8;
    int c = (i & 255) * 4;
    int sr = perm ? (((r & 3) << 10) + (r >> 2)) : r;
    float4 v = *reinterpret_cast<const float4*>(src + (size_t)sr * src_ld + coff + c);
    ushort4 o;
    o.x = f2b(v.x); o.y = f2b(v.y); o.z = f2b(v.z); o.w = f2b(v.w);
    *reinterpret_cast<ushort4*>(dst + (size_t)r * 1024 + c) = o;
}

__global__ void build_toks(const int* __restrict__ target, int* __restrict__ toks) {
    int idx = blockIdx.x * 256 + threadIdx.x;
    if (idx < T_ * B_) {
        int t = idx / B_, b = idx % B_;
        toks[idx] = (t == 0) ? 0 : target[b * T_ + t - 1];
    }
}

__global__ void build_bsum(const float* __restrict__ b_ih, const float* __restrict__ b_hh,
                           float* __restrict__ bsum) {
    int j = blockIdx.x * 256 + threadIdx.x;
    if (j < G4) {
        int pj = ((j & 3) << 10) + (j >> 2);
        bsum[j] = b_ih[pj] + b_hh[pj];
    }
}

// ---------- 64x64-tile bf16 MFMA GEMM (precompute only), BK=128, counted vmcnt ----------
template<int MODE>
__global__ __launch_bounds__(256) void gemm_mf(
    const unsigned short* __restrict__ A,
    const unsigned short* __restrict__ Bw,
    int K, int ldb, int ldc,
    float* __restrict__ C, unsigned short* __restrict__ Cb,
    const float* __restrict__ bias)
{
    __shared__ unsigned short As[2 * 8192];
    __shared__ unsigned short Bs[2 * 8192];
    const int tid = threadIdx.x;
    const int lane = tid & 63;
    const int wv = tid >> 6;
    const int m0 = blockIdx.x * 64;
    const int n0 = blockIdx.y * 64;

    const unsigned short* ga[4];
    const unsigned short* gb[4];
    #pragma unroll
    for (int j = 0; j < 4; ++j) {
        int ci = tid + 256 * j;
        int row = ci >> 4;
        int src = (ci & 15) ^ (row & 7);
        ga[j] = A + (size_t)(m0 + row) * K + src * 8;
        gb[j] = Bw + (size_t)(n0 + row) * ldb + src * 8;
    }

    f32x4 acc[2][2] = {};
    const int r0 = (wv >> 1) * 32;
    const int cq0 = (wv & 1) * 32;
    const int fr = lane & 15;
    const int kg = lane >> 4;

    auto stage = [&](int k0, int p) {
        #pragma unroll
        for (int j = 0; j < 4; ++j) {
            gll16(ga[j] + k0, As + p * 8192 + j * 2048 + wv * 512);
            gll16(gb[j] + k0, Bs + p * 8192 + j * 2048 + wv * 512);
        }
    };

    stage(0, 0);
    stage(128, 1);
    int p = 0;
    for (int k0 = 0; k0 < K; k0 += 128) {
        if (k0 + 128 < K) {
            asm volatile("s_waitcnt vmcnt(8)" ::: "memory");
        } else {
            asm volatile("s_waitcnt vmcnt(0)" ::: "memory");
        }
        __builtin_amdgcn_sched_barrier(0);
        __builtin_amdgcn_s_barrier();
        __builtin_amdgcn_sched_barrier(0);
        const unsigned short* Ab = As + p * 8192;
        const unsigned short* Bb = Bs + p * 8192;
        bf16x8 af[2][4], bfr[2][4];
        #pragma unroll
        for (int f = 0; f < 2; ++f)
            #pragma unroll
            for (int kh = 0; kh < 4; ++kh) {
                int ra = r0 + f * 16 + fr;
                af[f][kh] = *(const bf16x8*)&Ab[ra * 128 + (((kh * 4 + kg) ^ (ra & 7)) << 3)];
                int rb = cq0 + f * 16 + fr;
                bfr[f][kh] = *(const bf16x8*)&Bb[rb * 128 + (((kh * 4 + kg) ^ (rb & 7)) << 3)];
            }
        asm volatile("s_waitcnt lgkmcnt(0)" ::: "memory");
        __builtin_amdgcn_sched_barrier(0);
        __builtin_amdgcn_s_barrier();
        __builtin_amdgcn_sched_barrier(0);
        if (k0 + 256 < K) stage(k0 + 256, p);
        #pragma unroll
        for (int f = 0; f < 2; ++f)
            #pragma unroll
            for (int g = 0; g < 2; ++g)
                #pragma unroll
                for (int kh = 0; kh < 4; ++kh)
                    acc[f][g] = __builtin_amdgcn_mfma_f32_16x16x32_bf16(
                        af[f][kh], bfr[g][kh], acc[f][g], 0, 0, 0);
        p ^= 1;
    }

    const int erow = (lane >> 4) * 4;
    const int ecol = lane & 15;
    #pragma unroll
    for (int f = 0; f < 2; ++f) {
        #pragma unroll
        for (int g = 0; g < 2; ++g) {
            #pragma unroll
            for (int r = 0; r < 4; ++r) {
                int row = m0 + r0 + f * 16 + erow + r;
                int col = n0 + cq0 + g * 16 + ecol;
                float v = acc[f][g][r] + bias[col];
                if (MODE == 0) C[(size_t)row * ldc + col] = v;
                else Cb[(size_t)row * ldc + col] = f2b(v);
            }
        }
    }
}

// ---------- 64x32-tile bf16 MFMA GEMM, BK=128, counted vmcnt (per-step GEMMs) ----------
// MODE 0: C = v + bias[col]
// MODE 2: col<1024 -> Cq=q(+bias); col<5120 -> gates(+Pemb[tok]); else logits(t-1)+bias2
// MODE 4: gates-acc + fused LSTM pointwise epilogue
template<int MODE>
__global__ __launch_bounds__(256) void gemm_n32(
    const unsigned short* __restrict__ A,
    const unsigned short* __restrict__ Bw,
    int K, int ldb, int ldc,
    float* __restrict__ C, unsigned short* __restrict__ Cb,
    const float* __restrict__ bias,
    const float* __restrict__ Pemb,
    const int* __restrict__ toks,
    float* __restrict__ Cq,
    float* __restrict__ Lg,
    const float* __restrict__ bias2,
    int flag)
{
    __shared__ unsigned short As[2 * 8192];   // 64 x 128
    __shared__ unsigned short Bs[2 * 4096];   // 32 x 128
    const int tid = threadIdx.x;
    const int lane = tid & 63;
    const int wv = tid >> 6;
    const int m0 = blockIdx.x * 64;
    const int n0 = blockIdx.y * 32;

    const unsigned short* ga[4];
    const unsigned short* gb[2];
    #pragma unroll
    for (int j = 0; j < 4; ++j) {
        int ci = tid + 256 * j;
        int row = ci >> 4;
        int src = (ci & 15) ^ (row & 7);
        ga[j] = A + (size_t)(m0 + row) * K + src * 8;
    }
    #pragma unroll
    for (int j = 0; j < 2; ++j) {
        int ci = tid + 256 * j;
        int row = ci >> 4;
        int src = (ci & 15) ^ (row & 7);
        gb[j] = Bw + (size_t)(n0 + row) * ldb + src * 8;
    }

    f32x4 acc[2] = {};
    const int r0 = (wv >> 1) * 32;
    const int c0 = (wv & 1) * 16;
    const int fr = lane & 15;
    const int kg = lane >> 4;

    auto stage = [&](int k0, int p) {
        #pragma unroll
        for (int j = 0; j < 4; ++j)
            gll16(ga[j] + k0, As + p * 8192 + j * 2048 + wv * 512);
        #pragma unroll
        for (int j = 0; j < 2; ++j)
            gll16(gb[j] + k0, Bs + p * 4096 + j * 2048 + wv * 512);
    };

    stage(0, 0);
    stage(128, 1);
    int p = 0;
    for (int k0 = 0; k0 < K; k0 += 128) {
        if (k0 + 128 < K) {
            asm volatile("s_waitcnt vmcnt(6)" ::: "memory");
        } else {
            asm volatile("s_waitcnt vmcnt(0)" ::: "memory");
        }
        __builtin_amdgcn_sched_barrier(0);
        __builtin_amdgcn_s_barrier();
        __builtin_amdgcn_sched_barrier(0);
        const unsigned short* Ab = As + p * 8192;
        const unsigned short* Bb = Bs + p * 4096;
        bf16x8 af[2][4], bfr[4];
        #pragma unroll
        for (int kh = 0; kh < 4; ++kh) {
            #pragma unroll
            for (int f = 0; f < 2; ++f) {
                int ra = r0 + f * 16 + fr;
                af[f][kh] = *(const bf16x8*)&Ab[ra * 128 + (((kh * 4 + kg) ^ (ra & 7)) << 3)];
            }
            int rb = c0 + fr;
            bfr[kh] = *(const bf16x8*)&Bb[rb * 128 + (((kh * 4 + kg) ^ (rb & 7)) << 3)];
        }
        asm volatile("s_waitcnt lgkmcnt(0)" ::: "memory");
        __builtin_amdgcn_sched_barrier(0);
        __builtin_amdgcn_s_barrier();
        __builtin_amdgcn_sched_barrier(0);
        if (k0 + 256 < K) stage(k0 + 256, p);
        #pragma unroll
        for (int f = 0; f < 2; ++f)
            #pragma unroll
            for (int kh = 0; kh < 4; ++kh)
                acc[f] = __builtin_amdgcn_mfma_f32_16x16x32_bf16(
                    af[f][kh], bfr[kh], acc[f], 0, 0, 0);
        p ^= 1;
    }

    const int erow = (lane >> 4) * 4;
    const int ecol = lane & 15;

    if constexpr (MODE == 4) {
        __shared__ float Lt[64 * 32];
        __syncthreads();
        #pragma unroll
        for (int f = 0; f < 2; ++f)
            #pragma unroll
            for (int r = 0; r < 4; ++r)
                Lt[(r0 + f * 16 + erow + r) * 32 + c0 + ecol] = acc[f][r];
        __syncthreads();
        #pragma unroll
        for (int i = 0; i < 2; ++i) {
            int pi = tid + 256 * i;
            int r = pi >> 3, u = pi & 7;
            int b = m0 + r;
            int hh = (n0 >> 2) + u;
            f32x4 gv = *reinterpret_cast<const f32x4*>(&Lt[r * 32 + u * 4]);
            const float* gp = C + (size_t)b * G4 + n0 + u * 4;
            float iv = gv[0] + gp[0];
            float fv = gv[1] + gp[1];
            float gg = gv[2] + gp[2];
            float ov = gv[3] + gp[3];
            int ci = b * H_ + hh;
            float cn = fsigm(fv) * Cq[ci] + fsigm(iv) * ftanh(gg);
            float hn = fsigm(ov) * ftanh(cn);
            Cq[ci] = cn;
            Cb[ci] = f2b(hn);
            if (flag) Lg[ci] = hn;
        }
    } else {
        #pragma unroll
        for (int f = 0; f < 2; ++f) {
            #pragma unroll
            for (int r = 0; r < 4; ++r) {
                int row = m0 + r0 + f * 16 + erow + r;
                int col = n0 + c0 + ecol;
                float v = acc[f][r];
                if (MODE == 0) {
                    C[(size_t)row * ldc + col] = v + bias[col];
                } else {  // MODE 2
                    if (col < H_) {
                        Cq[(size_t)row * H_ + col] = v + bias[col];
                    } else if (col < 5120) {
                        int cg = col - H_;
                        C[(size_t)row * G4 + cg] = v + Pemb[(size_t)toks[row] * G4 + cg];
                    } else {
                        int cl = col - 5120;
                        Lg[(size_t)row * V_ + cl] = v + bias2[cl];
                    }
                }
            }
        }
    }
}

// ---------- attention energies + partial context (+ lsm of t-1), grid (B,16) x 256 ----------
__global__ __launch_bounds__(256) void attn_e(
    const unsigned short* __restrict__ kp,   // [B*S, H] bf16
    const float* __restrict__ q,             // [B, H]
    const float* __restrict__ Va,            // [H]
    const unsigned short* __restrict__ encb, // [B*S, H] bf16
    float* __restrict__ es_g,                // [B, S]
    float* __restrict__ pctx,                // [B, 16, H] unnormalized partial ctx
    const float* __restrict__ lg,            // [B, V] logits t-1
    float* __restrict__ lp,                  // [B,T,V]
    int t)
{
    const int b = blockIdx.x;
    const int sh = blockIdx.y;  // s-chunk of 16
    const int tid = threadIdx.x;
    const int lane = tid & 63;
    const int wv = tid >> 6;    // 0..3
    __shared__ float qs[H_];
    __shared__ float vas[H_];
    __shared__ float es[16], pe[16];
    __shared__ float redm[4], reds[4];

    *reinterpret_cast<float4*>(&qs[tid * 4]) =
        *reinterpret_cast<const float4*>(&q[(size_t)b * H_ + tid * 4]);
    *reinterpret_cast<float4*>(&vas[tid * 4]) =
        *reinterpret_cast<const float4*>(&Va[tid * 4]);

    // ---- log-softmax(t-1), sh==0 blocks only; barriers unconditional ----
    const bool doL = (t > 0) && (sh == 0);
    float a0 = doL ? lg[(size_t)b * V_ + tid] : -3.4e38f;
    float a1 = doL ? lg[(size_t)b * V_ + 256 + tid] : -3.4e38f;
    float mx = fmaxf(a0, a1);
    #pragma unroll
    for (int off = 32; off; off >>= 1) mx = fmaxf(mx, __shfl_xor(mx, off));
    if (lane == 0) redm[wv] = mx;
    __syncthreads();                         // also publishes qs/vas
    mx = fmaxf(fmaxf(redm[0], redm[1]), fmaxf(redm[2], redm[3]));
    float sm = doL ? (__expf(a0 - mx) + __expf(a1 - mx)) : 0.f;
    #pragma unroll
    for (int off = 32; off; off >>= 1) sm += __shfl_xor(sm, off);
    if (lane == 0) reds[wv] = sm;
    __syncthreads();
    if (doL) {
        sm = reds[0] + reds[1] + reds[2] + reds[3];
        float lse = mx + __logf(sm);
        size_t off = ((size_t)b * T_ + (t - 1)) * V_;
        lp[off + tid] = a0 - lse;
        lp[off + tid + 256] = a1 - lse;
    }

    // ---- energies: wave wv handles s_loc = wv*4 + 0..3 ----
    #pragma unroll
    for (int si = 0; si < 4; ++si) {
        int s_loc = wv * 4 + si;
        const unsigned short* kr = kp + (size_t)(b * S_ + sh * 16 + s_loc) * H_;
        float acc = 0.f;
        #pragma unroll
        for (int it = 0; it < 4; ++it) {
            int h4 = lane * 4 + it * 256;
            ushort4 u = *reinterpret_cast<const ushort4*>(kr + h4);
            acc += vas[h4 + 0] * ftanh(qs[h4 + 0] + bf2f(u.x));
            acc += vas[h4 + 1] * ftanh(qs[h4 + 1] + bf2f(u.y));
            acc += vas[h4 + 2] * ftanh(qs[h4 + 2] + bf2f(u.z));
            acc += vas[h4 + 3] * ftanh(qs[h4 + 3] + bf2f(u.w));
        }
        #pragma unroll
        for (int off = 32; off; off >>= 1) acc += __shfl_down(acc, off);
        if (lane == 0) {
            es[s_loc] = acc;
            es_g[(size_t)b * S_ + sh * 16 + s_loc] = acc;
        }
    }
    __syncthreads();

    // ---- partial context with local-max scaling ----
    float mb = es[0];
    #pragma unroll
    for (int i = 1; i < 16; ++i) mb = fmaxf(mb, es[i]);
    if (tid < 16) pe[tid] = __expf(es[tid] - mb);
    __syncthreads();
    const int c0 = tid * 4;
    float ax = 0.f, ay = 0.f, az = 0.f, aw = 0.f;
    #pragma unroll
    for (int sl = 0; sl < 16; ++sl) {
        ushort4 u = *reinterpret_cast<const ushort4*>(
            &encb[(size_t)(b * S_ + sh * 16 + sl) * H_ + c0]);
        float w = pe[sl];
        ax += w * bf2f(u.x);
        ay += w * bf2f(u.y);
        az += w * bf2f(u.z);
        aw += w * bf2f(u.w);
    }
    float4 o4; o4.x = ax; o4.y = ay; o4.z = az; o4.w = aw;
    *reinterpret_cast<float4*>(&pctx[((size_t)b * 16 + sh) * H_ + c0]) = o4;
}

// ---------- combine: exact softmax + attn-weight store + ctx finalize, grid B x 256 ----------
__global__ __launch_bounds__(256) void attn_comb(
    const float* __restrict__ es_g,          // [B, S]
    const float* __restrict__ pctx,          // [B, 16, H]
    unsigned short* __restrict__ ctxb,       // [B, H] bf16
    float* __restrict__ attnOut,             // [B,T,S]
    int t)
{
    const int b = blockIdx.x;
    const int tid = threadIdx.x;
    const int lane = tid & 63;
    const int wv = tid >> 6;
    __shared__ float es[S_], sc[16];
    __shared__ float redm[4], reds[4];

    float x = es_g[(size_t)b * S_ + tid];
    es[tid] = x;
    float mx = x;
    #pragma unroll
    for (int off = 32; off; off >>= 1) mx = fmaxf(mx, __shfl_xor(mx, off));
    if (lane == 0) redm[wv] = mx;
    __syncthreads();                          // publishes es too
    mx = fmaxf(fmaxf(redm[0], redm[1]), fmaxf(redm[2], redm[3]));
    float ex = __expf(x - mx);
    float sm = ex;
    #pragma unroll
    for (int off = 32; off; off >>= 1) sm += __shfl_xor(sm, off);
    if (lane == 0) reds[wv] = sm;
    __syncthreads();
    sm = reds[0] + reds[1] + reds[2] + reds[3];
    float rZ = __builtin_amdgcn_rcpf(sm);
    attnOut[((size_t)(b * T_ + t)) * S_ + tid] = ex * rZ;
    if (tid < 16) {
        float mb = es[tid * 16];
        #pragma unroll
        for (int j = 1; j < 16; ++j) mb = fmaxf(mb, es[tid * 16 + j]);
        sc[tid] = __expf(mb - mx);
    }
    __syncthreads();
    const int c0 = tid * 4;
    float ax = 0.f, ay = 0.f, az = 0.f, aw = 0.f;
    #pragma unroll
    for (int blk = 0; blk < 16; ++blk) {
        float4 pv = *reinterpret_cast<const float4*>(
            &pctx[((size_t)b * 16 + blk) * H_ + c0]);
        float s = sc[blk];
        ax += s * pv.x; ay += s * pv.y; az += s * pv.z; aw += s * pv.w;
    }
    ushort4 o;
    o.x = f2b(ax * rZ); o.y = f2b(ay * rZ); o.z = f2b(az * rZ); o.w = f2b(aw * rZ);
    *reinterpret_cast<ushort4*>(&ctxb[(size_t)b * H_ + c0]) = o;
}

// ---------- standalone log-softmax (final step only) ----------
__global__ __launch_bounds__(256) void lsm_kernel(
    const float* __restrict__ lg, float* __restrict__ lp, int t)
{
    int b = blockIdx.x, tid = threadIdx.x;
    int lane = tid & 63, wv = tid >> 6;
    __shared__ float red[4];
    float a0 = lg[(size_t)b * V_ + tid];
    float a1 = lg[(size_t)b * V_ + 256 + tid];
    float mx = fmaxf(a0, a1);
    #pragma unroll
    for (int off = 32; off; off >>= 1) mx = fmaxf(mx, __shfl_xor(mx, off));
    if (lane == 0) red[wv] = mx;
    __syncthreads();
    mx = fmaxf(fmaxf(red[0], red[1]), fmaxf(red[2], red[3]));
    float sm = __expf(a0 - mx) + __expf(a1 - mx);
    #pragma unroll
    for (int off = 32; off; off >>= 1) sm += __shfl_xor(sm, off);
    __syncthreads();
    if (lane == 0) red[wv] = sm;
    __syncthreads();
    sm = red[0] + red[1] + red[2] + red[3];
    float lse = mx + __logf(sm);
    size_t off = ((size_t)b * T_ + t) * V_;
    lp[off + tid] = a0 - lse;
    lp[off + tid + 256] = a1 - lse;
}

// ---------- launch ----------
extern "C" void kernel_launch(void* const* d_in, const int* in_sizes, int n_in,
                              void* d_out, int out_size, void* d_ws, size_t ws_size,
                              hipStream_t stream) {
    const float* enc   = (const float*)d_in[0];
    const float* h0    = (const float*)d_in[1];
    const float* c0    = (const float*)d_in[2];
    const int*   targ  = (const int*)d_in[3];
    const float* emb   = (const float*)d_in[5];
    const float* Wa_w  = (const float*)d_in[6];
    const float* Wa_b  = (const float*)d_in[7];
    const float* Ua_w  = (const float*)d_in[8];
    const float* Ua_b  = (const float*)d_in[9];
    const float* Va_w  = (const float*)d_in[10];
    const float* W_ih  = (const float*)d_in[12];
    const float* W_hh  = (const float*)d_in[13];
    const float* b_ih  = (const float*)d_in[14];
    const float* b_hh  = (const float*)d_in[15];
    const float* out_w = (const float*)d_in[16];
    const float* out_b = (const float*)d_in[17];

    float* out  = (float*)d_out;
    float* lp   = out;                          // [B,T,V]
    float* hid  = out + (size_t)B_ * T_ * V_;   // [1,B,H]
    float* attn = hid + (size_t)B_ * H_;        // [B,T,S]

    char* w = (char*)d_ws;
    auto alloc = [&](size_t bytes) {
        char* p = w;
        w += (bytes + 255) & ~(size_t)255;
        return p;
    };
    const size_t NKP = (size_t)B_ * S_ * H_;
    unsigned short* kp     = (unsigned short*)alloc(NKP * 2);
    unsigned short* encb   = (unsigned short*)alloc(NKP * 2);
    unsigned short* Wcat_b = (unsigned short*)alloc((size_t)5632 * H_ * 2); // [Wa; W_hh(perm); out_w]
    unsigned short* Wih1_b = (unsigned short*)alloc((size_t)G4 * H_ * 2);   // W_ih[:, :H] perm
    unsigned short* Wih2_b = (unsigned short*)alloc((size_t)G4 * H_ * 2);   // W_ih[:, H:] perm
    unsigned short* Uaw_b  = (unsigned short*)alloc((size_t)H_ * H_ * 2);
    unsigned short* emb_b  = (unsigned short*)alloc((size_t)V_ * H_ * 2);
    unsigned short* hb     = (unsigned short*)alloc((size_t)B_ * H_ * 2);
    unsigned short* ctxb   = (unsigned short*)alloc((size_t)B_ * H_ * 2);
    float* Pemb  = (float*)alloc((size_t)V_ * G4 * 4);
    float* bsumP = (float*)alloc((size_t)G4 * 4);
    int*   toks  = (int*)alloc((size_t)T_ * B_ * 4);
    float* cbuf  = (float*)alloc((size_t)B_ * H_ * 4);
    float* qbuf  = (float*)alloc((size_t)B_ * H_ * 4);
    float* gates = (float*)alloc((size_t)B_ * G4 * 4);
    float* lgbuf = (float*)alloc((size_t)B_ * V_ * 4);
    float* es_g  = (float*)alloc((size_t)B_ * S_ * 4);
    float* pctx  = (float*)alloc((size_t)B_ * 16 * H_ * 4);
    if ((size_t)(w - (char*)d_ws) > ws_size) return;

    auto cvt = [&](const float* src, unsigned short* dst, size_t n) {
        int n4 = (int)(n / 4);
        f32_to_bf16_x4<<<(n4 + 255) / 256, 256, 0, stream>>>((const float4*)src, (ushort4*)dst, n4);
    };

    // precompute
    cvt(enc, encb, NKP);
    cvt(Ua_w, Uaw_b, (size_t)H_ * H_);
    cvt(emb, emb_b, (size_t)V_ * H_);
    cvt(h0, hb, (size_t)B_ * H_);
    cvt_gather<<<1024, 256, 0, stream>>>(Wa_w, H_, 0, Wcat_b, 0);
    cvt_gather<<<4096, 256, 0, stream>>>(W_hh, H_, 0, Wcat_b + (size_t)1024 * H_, 1);
    cvt_gather<<<512, 256, 0, stream>>>(out_w, H_, 0, Wcat_b + (size_t)5120 * H_, 0);
    cvt_gather<<<4096, 256, 0, stream>>>(W_ih, 2 * H_, 0, Wih1_b, 1);
    cvt_gather<<<4096, 256, 0, stream>>>(W_ih, 2 * H_, H_, Wih2_b, 1);
    build_toks<<<(T_ * B_ + 255) / 256, 256, 0, stream>>>(targ, toks);
    build_bsum<<<(G4 + 255) / 256, 256, 0, stream>>>(b_ih, b_hh, bsumP);
    hipMemcpyAsync(cbuf, c0, (size_t)B_ * H_ * 4, hipMemcpyDeviceToDevice, stream);

    // keys_proj: kp = encb @ Ua_w^T + Ua_b (bf16 out)
    gemm_mf<1><<<dim3((B_ * S_) / 64, H_ / 64), 256, 0, stream>>>(
        encb, Uaw_b, H_, H_, H_, nullptr, kp, Ua_b);
    // Pemb (permuted): emb @ W_ih[:, :H](perm)^T + bsumP
    gemm_mf<0><<<dim3(V_ / 64, G4 / 64), 256, 0, stream>>>(
        emb_b, Wih1_b, H_, H_, G4, Pemb, nullptr, bsumP);

    // sequential decode: 4 launches per step
    for (int t = 0; t < T_; ++t) {
        gemm_n32<2><<<dim3(2, 176), 256, 0, stream>>>(
            hb, Wcat_b, H_, H_, 0, gates, nullptr, Wa_b,
            Pemb, toks + t * B_, qbuf, lgbuf, out_b, 0);
        attn_e<<<dim3(B_, 16), 256, 0, stream>>>(
            kp, qbuf, Va_w, encb, es_g, pctx, lgbuf, lp, t);
        attn_comb<<<B_, 256, 0, stream>>>(es_g, pctx, ctxb, attn, t);
        gemm_n32<4><<<dim3(2, 128), 256, 0, stream>>>(
            ctxb, Wih2_b, H_, H_, 0, gates, hb, nullptr,
            nullptr, nullptr, cbuf, hid, nullptr, t == T_ - 1);
    }
    // logits + lsm for final step
    gemm_n32<0><<<dim3(2, 16), 256, 0, stream>>>(
        hb, Wcat_b + (size_t)5120 * H_, H_, H_, V_, lgbuf, nullptr, out_b,
        nullptr, nullptr, nullptr, nullptr, nullptr, 0);
    lsm_kernel<<<B_, 256, 0, stream>>>(lgbuf, lp, T_ - 1);
}

// Round 8
// 6266.276 us; speedup vs baseline: 6.6976x; 1.0081x over previous
//
#include <hip/hip_runtime.h>

#define B_ 128
#define S_ 256
#define H_ 1024
#define V_ 512
#define T_ 128
#define G4 4096

typedef __attribute__((ext_vector_type(8))) short bf16x8;
typedef __attribute__((ext_vector_type(4))) float f32x4;

// ---------- helpers ----------
__device__ __forceinline__ float bf2f(unsigned short x) {
    unsigned int u = ((unsigned int)x) << 16;
    return __builtin_bit_cast(float, u);
}
__device__ __forceinline__ unsigned short f2b(float f) {
    unsigned int u = __builtin_bit_cast(unsigned int, f);
    u = u + 0x7fffu + ((u >> 16) & 1u);
    return (unsigned short)(u >> 16);
}
__device__ __forceinline__ float ftanh(float x) {
    float e = __expf(2.f * x);
    return 1.f - 2.f * __builtin_amdgcn_rcpf(e + 1.f);
}
__device__ __forceinline__ float fsigm(float x) {
    return __builtin_amdgcn_rcpf(1.f + __expf(-x));
}
__device__ __forceinline__ void gll16(const void* g, void* l) {
    __builtin_amdgcn_global_load_lds(
        (const __attribute__((address_space(1))) unsigned int*)g,
        (__attribute__((address_space(3))) unsigned int*)l, 16, 0, 0);
}

// ---------- small precompute kernels ----------
__global__ void f32_to_bf16_x4(const float4* __restrict__ in, ushort4* __restrict__ out, int n4) {
    int i = blockIdx.x * 256 + threadIdx.x;
    if (i < n4) {
        float4 v = in[i];
        ushort4 o;
        o.x = f2b(v.x); o.y = f2b(v.y); o.z = f2b(v.z); o.w = f2b(v.w);
        out[i] = o;
    }
}

__global__ void cvt_gather(const float* __restrict__ src, int src_ld, int coff,
                           unsigned short* __restrict__ dst, int perm) {
    int i = blockIdx.x * 256 + threadIdx.x;
    int r = i >> 8;
    int c = (i & 255) * 4;
    int sr = perm ? (((r & 3) << 10) + (r >> 2)) : r;
    float4 v = *reinterpret_cast<const float4*>(src + (size_t)sr * src_ld + coff + c);
    ushort4 o;
    o.x = f2b(v.x); o.y = f2b(v.y); o.z = f2b(v.z); o.w = f2b(v.w);
    *reinterpret_cast<ushort4*>(dst + (size_t)r * 1024 + c) = o;
}

__global__ void build_toks(const int* __restrict__ target, int* __restrict__ toks) {
    int idx = blockIdx.x * 256 + threadIdx.x;
    if (idx < T_ * B_) {
        int t = idx / B_, b = idx % B_;
        toks[idx] = (t == 0) ? 0 : target[b * T_ + t - 1];
    }
}

__global__ void build_bsum(const float* __restrict__ b_ih, const float* __restrict__ b_hh,
                           float* __restrict__ bsum) {
    int j = blockIdx.x * 256 + threadIdx.x;
    if (j < G4) {
        int pj = ((j & 3) << 10) + (j >> 2);
        bsum[j] = b_ih[pj] + b_hh[pj];
    }
}

// ---------- 64x64-tile bf16 MFMA GEMM (precompute only), BK=128, counted vmcnt ----------
template<int MODE>
__global__ __launch_bounds__(256) void gemm_mf(
    const unsigned short* __restrict__ A,
    const unsigned short* __restrict__ Bw,
    int K, int ldb, int ldc,
    float* __restrict__ C, unsigned short* __restrict__ Cb,
    const float* __restrict__ bias)
{
    __shared__ unsigned short As[2 * 8192];
    __shared__ unsigned short Bs[2 * 8192];
    const int tid = threadIdx.x;
    const int lane = tid & 63;
    const int wv = tid >> 6;
    const int m0 = blockIdx.x * 64;
    const int n0 = blockIdx.y * 64;

    const unsigned short* ga[4];
    const unsigned short* gb[4];
    #pragma unroll
    for (int j = 0; j < 4; ++j) {
        int ci = tid + 256 * j;
        int row = ci >> 4;
        int src = (ci & 15) ^ (row & 7);
        ga[j] = A + (size_t)(m0 + row) * K + src * 8;
        gb[j] = Bw + (size_t)(n0 + row) * ldb + src * 8;
    }

    f32x4 acc[2][2] = {};
    const int r0 = (wv >> 1) * 32;
    const int cq0 = (wv & 1) * 32;
    const int fr = lane & 15;
    const int kg = lane >> 4;

    auto stage = [&](int k0, int p) {
        #pragma unroll
        for (int j = 0; j < 4; ++j) {
            gll16(ga[j] + k0, As + p * 8192 + j * 2048 + wv * 512);
            gll16(gb[j] + k0, Bs + p * 8192 + j * 2048 + wv * 512);
        }
    };

    stage(0, 0);
    stage(128, 1);
    int p = 0;
    for (int k0 = 0; k0 < K; k0 += 128) {
        if (k0 + 128 < K) {
            asm volatile("s_waitcnt vmcnt(8)" ::: "memory");
        } else {
            asm volatile("s_waitcnt vmcnt(0)" ::: "memory");
        }
        __builtin_amdgcn_sched_barrier(0);
        __builtin_amdgcn_s_barrier();
        __builtin_amdgcn_sched_barrier(0);
        const unsigned short* Ab = As + p * 8192;
        const unsigned short* Bb = Bs + p * 8192;
        bf16x8 af[2][4], bfr[2][4];
        #pragma unroll
        for (int f = 0; f < 2; ++f)
            #pragma unroll
            for (int kh = 0; kh < 4; ++kh) {
                int ra = r0 + f * 16 + fr;
                af[f][kh] = *(const bf16x8*)&Ab[ra * 128 + (((kh * 4 + kg) ^ (ra & 7)) << 3)];
                int rb = cq0 + f * 16 + fr;
                bfr[f][kh] = *(const bf16x8*)&Bb[rb * 128 + (((kh * 4 + kg) ^ (rb & 7)) << 3)];
            }
        asm volatile("s_waitcnt lgkmcnt(0)" ::: "memory");
        __builtin_amdgcn_sched_barrier(0);
        __builtin_amdgcn_s_barrier();
        __builtin_amdgcn_sched_barrier(0);
        if (k0 + 256 < K) stage(k0 + 256, p);
        __builtin_amdgcn_s_setprio(1);
        #pragma unroll
        for (int f = 0; f < 2; ++f)
            #pragma unroll
            for (int g = 0; g < 2; ++g)
                #pragma unroll
                for (int kh = 0; kh < 4; ++kh)
                    acc[f][g] = __builtin_amdgcn_mfma_f32_16x16x32_bf16(
                        af[f][kh], bfr[g][kh], acc[f][g], 0, 0, 0);
        __builtin_amdgcn_s_setprio(0);
        p ^= 1;
    }

    const int erow = (lane >> 4) * 4;
    const int ecol = lane & 15;
    #pragma unroll
    for (int f = 0; f < 2; ++f) {
        #pragma unroll
        for (int g = 0; g < 2; ++g) {
            #pragma unroll
            for (int r = 0; r < 4; ++r) {
                int row = m0 + r0 + f * 16 + erow + r;
                int col = n0 + cq0 + g * 16 + ecol;
                float v = acc[f][g][r] + bias[col];
                if (MODE == 0) C[(size_t)row * ldc + col] = v;
                else Cb[(size_t)row * ldc + col] = f2b(v);
            }
        }
    }
}

// ---------- 64x32-tile bf16 MFMA GEMM, BK=128, counted vmcnt (per-step GEMMs) ----------
// MODE 0: C = v + bias[col]
// MODE 2: col<1024 -> Cq=q(+bias); col<5120 -> gates(+Pemb[tok]); else logits(t-1)+bias2
// MODE 4: gates-acc + fused LSTM pointwise epilogue
template<int MODE>
__global__ __launch_bounds__(256) void gemm_n32(
    const unsigned short* __restrict__ A,
    const unsigned short* __restrict__ Bw,
    int K, int ldb, int ldc,
    float* __restrict__ C, unsigned short* __restrict__ Cb,
    const float* __restrict__ bias,
    const float* __restrict__ Pemb,
    const int* __restrict__ toks,
    float* __restrict__ Cq,
    float* __restrict__ Lg,
    const float* __restrict__ bias2,
    int flag)
{
    __shared__ unsigned short As[2 * 8192];   // 64 x 128
    __shared__ unsigned short Bs[2 * 4096];   // 32 x 128
    const int tid = threadIdx.x;
    const int lane = tid & 63;
    const int wv = tid >> 6;
    const int m0 = blockIdx.x * 64;
    const int n0 = blockIdx.y * 32;

    const unsigned short* ga[4];
    const unsigned short* gb[2];
    #pragma unroll
    for (int j = 0; j < 4; ++j) {
        int ci = tid + 256 * j;
        int row = ci >> 4;
        int src = (ci & 15) ^ (row & 7);
        ga[j] = A + (size_t)(m0 + row) * K + src * 8;
    }
    #pragma unroll
    for (int j = 0; j < 2; ++j) {
        int ci = tid + 256 * j;
        int row = ci >> 4;
        int src = (ci & 15) ^ (row & 7);
        gb[j] = Bw + (size_t)(n0 + row) * ldb + src * 8;
    }

    f32x4 acc[2] = {};
    const int r0 = (wv >> 1) * 32;
    const int c0 = (wv & 1) * 16;
    const int fr = lane & 15;
    const int kg = lane >> 4;

    auto stage = [&](int k0, int p) {
        #pragma unroll
        for (int j = 0; j < 4; ++j)
            gll16(ga[j] + k0, As + p * 8192 + j * 2048 + wv * 512);
        #pragma unroll
        for (int j = 0; j < 2; ++j)
            gll16(gb[j] + k0, Bs + p * 4096 + j * 2048 + wv * 512);
    };

    stage(0, 0);
    stage(128, 1);
    int p = 0;
    for (int k0 = 0; k0 < K; k0 += 128) {
        if (k0 + 128 < K) {
            asm volatile("s_waitcnt vmcnt(6)" ::: "memory");
        } else {
            asm volatile("s_waitcnt vmcnt(0)" ::: "memory");
        }
        __builtin_amdgcn_sched_barrier(0);
        __builtin_amdgcn_s_barrier();
        __builtin_amdgcn_sched_barrier(0);
        const unsigned short* Ab = As + p * 8192;
        const unsigned short* Bb = Bs + p * 4096;
        bf16x8 af[2][4], bfr[4];
        #pragma unroll
        for (int kh = 0; kh < 4; ++kh) {
            #pragma unroll
            for (int f = 0; f < 2; ++f) {
                int ra = r0 + f * 16 + fr;
                af[f][kh] = *(const bf16x8*)&Ab[ra * 128 + (((kh * 4 + kg) ^ (ra & 7)) << 3)];
            }
            int rb = c0 + fr;
            bfr[kh] = *(const bf16x8*)&Bb[rb * 128 + (((kh * 4 + kg) ^ (rb & 7)) << 3)];
        }
        asm volatile("s_waitcnt lgkmcnt(0)" ::: "memory");
        __builtin_amdgcn_sched_barrier(0);
        __builtin_amdgcn_s_barrier();
        __builtin_amdgcn_sched_barrier(0);
        if (k0 + 256 < K) stage(k0 + 256, p);
        __builtin_amdgcn_s_setprio(1);
        #pragma unroll
        for (int f = 0; f < 2; ++f)
            #pragma unroll
            for (int kh = 0; kh < 4; ++kh)
                acc[f] = __builtin_amdgcn_mfma_f32_16x16x32_bf16(
                    af[f][kh], bfr[kh], acc[f], 0, 0, 0);
        __builtin_amdgcn_s_setprio(0);
        p ^= 1;
    }

    const int erow = (lane >> 4) * 4;
    const int ecol = lane & 15;

    if constexpr (MODE == 4) {
        __shared__ float Lt[64 * 32];
        __syncthreads();
        #pragma unroll
        for (int f = 0; f < 2; ++f)
            #pragma unroll
            for (int r = 0; r < 4; ++r)
                Lt[(r0 + f * 16 + erow + r) * 32 + c0 + ecol] = acc[f][r];
        __syncthreads();
        #pragma unroll
        for (int i = 0; i < 2; ++i) {
            int pi = tid + 256 * i;
            int r = pi >> 3, u = pi & 7;
            int b = m0 + r;
            int hh = (n0 >> 2) + u;
            f32x4 gv = *reinterpret_cast<const f32x4*>(&Lt[r * 32 + u * 4]);
            const float* gp = C + (size_t)b * G4 + n0 + u * 4;
            float iv = gv[0] + gp[0];
            float fv = gv[1] + gp[1];
            float gg = gv[2] + gp[2];
            float ov = gv[3] + gp[3];
            int ci = b * H_ + hh;
            float cn = fsigm(fv) * Cq[ci] + fsigm(iv) * ftanh(gg);
            float hn = fsigm(ov) * ftanh(cn);
            Cq[ci] = cn;
            Cb[ci] = f2b(hn);
            if (flag) Lg[ci] = hn;
        }
    } else {
        #pragma unroll
        for (int f = 0; f < 2; ++f) {
            #pragma unroll
            for (int r = 0; r < 4; ++r) {
                int row = m0 + r0 + f * 16 + erow + r;
                int col = n0 + c0 + ecol;
                float v = acc[f][r];
                if (MODE == 0) {
                    C[(size_t)row * ldc + col] = v + bias[col];
                } else {  // MODE 2
                    if (col < H_) {
                        Cq[(size_t)row * H_ + col] = v + bias[col];
                    } else if (col < 5120) {
                        int cg = col - H_;
                        C[(size_t)row * G4 + cg] = v + Pemb[(size_t)toks[row] * G4 + cg];
                    } else {
                        int cl = col - 5120;
                        Lg[(size_t)row * V_ + cl] = v + bias2[cl];
                    }
                }
            }
        }
    }
}

// ---------- attention energies + raw-exp partial context (+ lsm of t-1), grid (B,16) x 256 ----------
// Energies are bounded: |e| <= sum|Va| ~ 25 -> raw exp is overflow-safe in f32.
__global__ __launch_bounds__(256) void attn_e(
    const unsigned short* __restrict__ kp,   // [B*S, H] bf16
    const float* __restrict__ q,             // [B, H]
    const float* __restrict__ Va,            // [H]
    const unsigned short* __restrict__ encb, // [B*S, H] bf16
    float* __restrict__ es_g,                // [B, S]
    float* __restrict__ pctx,                // [B, 16, H] raw-exp-weighted partial ctx
    const float* __restrict__ lg,            // [B, V] logits t-1
    float* __restrict__ lp,                  // [B,T,V]
    int t)
{
    const int b = blockIdx.x;
    const int sh = blockIdx.y;  // s-chunk of 16
    const int tid = threadIdx.x;
    const int lane = tid & 63;
    const int wv = tid >> 6;    // 0..3
    __shared__ float qs[H_];
    __shared__ float vas[H_];
    __shared__ float pe[16];
    __shared__ float redm[4], reds[4];

    *reinterpret_cast<float4*>(&qs[tid * 4]) =
        *reinterpret_cast<const float4*>(&q[(size_t)b * H_ + tid * 4]);
    *reinterpret_cast<float4*>(&vas[tid * 4]) =
        *reinterpret_cast<const float4*>(&Va[tid * 4]);

    // ---- log-softmax(t-1), sh==0 blocks only; barriers unconditional ----
    const bool doL = (t > 0) && (sh == 0);
    float a0 = doL ? lg[(size_t)b * V_ + tid] : -3.4e38f;
    float a1 = doL ? lg[(size_t)b * V_ + 256 + tid] : -3.4e38f;
    float mx = fmaxf(a0, a1);
    #pragma unroll
    for (int off = 32; off; off >>= 1) mx = fmaxf(mx, __shfl_xor(mx, off));
    if (lane == 0) redm[wv] = mx;
    __syncthreads();                         // also publishes qs/vas
    mx = fmaxf(fmaxf(redm[0], redm[1]), fmaxf(redm[2], redm[3]));
    float sm = doL ? (__expf(a0 - mx) + __expf(a1 - mx)) : 0.f;
    #pragma unroll
    for (int off = 32; off; off >>= 1) sm += __shfl_xor(sm, off);
    if (lane == 0) reds[wv] = sm;
    __syncthreads();
    if (doL) {
        sm = reds[0] + reds[1] + reds[2] + reds[3];
        float lse = mx + __logf(sm);
        size_t off = ((size_t)b * T_ + (t - 1)) * V_;
        lp[off + tid] = a0 - lse;
        lp[off + tid + 256] = a1 - lse;
    }

    // ---- energies: wave wv handles s_loc = wv*4 + 0..3 ----
    #pragma unroll
    for (int si = 0; si < 4; ++si) {
        int s_loc = wv * 4 + si;
        const unsigned short* kr = kp + (size_t)(b * S_ + sh * 16 + s_loc) * H_;
        float acc = 0.f;
        #pragma unroll
        for (int it = 0; it < 4; ++it) {
            int h4 = lane * 4 + it * 256;
            ushort4 u = *reinterpret_cast<const ushort4*>(kr + h4);
            acc += vas[h4 + 0] * ftanh(qs[h4 + 0] + bf2f(u.x));
            acc += vas[h4 + 1] * ftanh(qs[h4 + 1] + bf2f(u.y));
            acc += vas[h4 + 2] * ftanh(qs[h4 + 2] + bf2f(u.z));
            acc += vas[h4 + 3] * ftanh(qs[h4 + 3] + bf2f(u.w));
        }
        #pragma unroll
        for (int off = 32; off; off >>= 1) acc += __shfl_down(acc, off);
        if (lane == 0) {
            pe[s_loc] = __expf(acc);
            es_g[(size_t)b * S_ + sh * 16 + s_loc] = acc;
        }
    }
    __syncthreads();

    // ---- raw-exp-weighted partial context ----
    const int c0 = tid * 4;
    float ax = 0.f, ay = 0.f, az = 0.f, aw = 0.f;
    #pragma unroll
    for (int sl = 0; sl < 16; ++sl) {
        ushort4 u = *reinterpret_cast<const ushort4*>(
            &encb[(size_t)(b * S_ + sh * 16 + sl) * H_ + c0]);
        float w = pe[sl];
        ax += w * bf2f(u.x);
        ay += w * bf2f(u.y);
        az += w * bf2f(u.z);
        aw += w * bf2f(u.w);
    }
    float4 o4; o4.x = ax; o4.y = ay; o4.z = az; o4.w = aw;
    *reinterpret_cast<float4*>(&pctx[((size_t)b * 16 + sh) * H_ + c0]) = o4;
}

// ---------- combine: Z-sum + attn-weight store + ctx finalize, grid (B,2) x 256 ----------
__global__ __launch_bounds__(256) void attn_comb(
    const float* __restrict__ es_g,          // [B, S]
    const float* __restrict__ pctx,          // [B, 16, H]
    unsigned short* __restrict__ ctxb,       // [B, H] bf16
    float* __restrict__ attnOut,             // [B,T,S]
    int t)
{
    const int b = blockIdx.x;
    const int hh = blockIdx.y;  // h-half (512 cols)
    const int tid = threadIdx.x;
    const int lane = tid & 63;
    const int wv = tid >> 6;
    __shared__ float reds[4];

    float ex = __expf(es_g[(size_t)b * S_ + tid]);
    float sm = ex;
    #pragma unroll
    for (int off = 32; off; off >>= 1) sm += __shfl_xor(sm, off);
    if (lane == 0) reds[wv] = sm;
    __syncthreads();
    sm = reds[0] + reds[1] + reds[2] + reds[3];
    float rZ = __builtin_amdgcn_rcpf(sm);
    if (hh == 0) attnOut[((size_t)(b * T_ + t)) * S_ + tid] = ex * rZ;

    const int c0 = hh * 512 + tid * 2;
    float a0 = 0.f, a1 = 0.f;
    #pragma unroll
    for (int blk = 0; blk < 16; ++blk) {
        float2 pv = *reinterpret_cast<const float2*>(
            &pctx[((size_t)b * 16 + blk) * H_ + c0]);
        a0 += pv.x; a1 += pv.y;
    }
    ushort2 o; o.x = f2b(a0 * rZ); o.y = f2b(a1 * rZ);
    *reinterpret_cast<ushort2*>(&ctxb[(size_t)b * H_ + c0]) = o;
}

// ---------- standalone log-softmax (final step only) ----------
__global__ __launch_bounds__(256) void lsm_kernel(
    const float* __restrict__ lg, float* __restrict__ lp, int t)
{
    int b = blockIdx.x, tid = threadIdx.x;
    int lane = tid & 63, wv = tid >> 6;
    __shared__ float red[4];
    float a0 = lg[(size_t)b * V_ + tid];
    float a1 = lg[(size_t)b * V_ + 256 + tid];
    float mx = fmaxf(a0, a1);
    #pragma unroll
    for (int off = 32; off; off >>= 1) mx = fmaxf(mx, __shfl_xor(mx, off));
    if (lane == 0) red[wv] = mx;
    __syncthreads();
    mx = fmaxf(fmaxf(red[0], red[1]), fmaxf(red[2], red[3]));
    float sm = __expf(a0 - mx) + __expf(a1 - mx);
    #pragma unroll
    for (int off = 32; off; off >>= 1) sm += __shfl_xor(sm, off);
    __syncthreads();
    if (lane == 0) red[wv] = sm;
    __syncthreads();
    sm = red[0] + red[1] + red[2] + red[3];
    float lse = mx + __logf(sm);
    size_t off = ((size_t)b * T_ + t) * V_;
    lp[off + tid] = a0 - lse;
    lp[off + tid + 256] = a1 - lse;
}

// ---------- launch ----------
extern "C" void kernel_launch(void* const* d_in, const int* in_sizes, int n_in,
                              void* d_out, int out_size, void* d_ws, size_t ws_size,
                              hipStream_t stream) {
    const float* enc   = (const float*)d_in[0];
    const float* h0    = (const float*)d_in[1];
    const float* c0    = (const float*)d_in[2];
    const int*   targ  = (const int*)d_in[3];
    const float* emb   = (const float*)d_in[5];
    const float* Wa_w  = (const float*)d_in[6];
    const float* Wa_b  = (const float*)d_in[7];
    const float* Ua_w  = (const float*)d_in[8];
    const float* Ua_b  = (const float*)d_in[9];
    const float* Va_w  = (const float*)d_in[10];
    const float* W_ih  = (const float*)d_in[12];
    const float* W_hh  = (const float*)d_in[13];
    const float* b_ih  = (const float*)d_in[14];
    const float* b_hh  = (const float*)d_in[15];
    const float* out_w = (const float*)d_in[16];
    const float* out_b = (const float*)d_in[17];

    float* out  = (float*)d_out;
    float* lp   = out;                          // [B,T,V]
    float* hid  = out + (size_t)B_ * T_ * V_;   // [1,B,H]
    float* attn = hid + (size_t)B_ * H_;        // [B,T,S]

    char* w = (char*)d_ws;
    auto alloc = [&](size_t bytes) {
        char* p = w;
        w += (bytes + 255) & ~(size_t)255;
        return p;
    };
    const size_t NKP = (size_t)B_ * S_ * H_;
    unsigned short* kp     = (unsigned short*)alloc(NKP * 2);
    unsigned short* encb   = (unsigned short*)alloc(NKP * 2);
    unsigned short* Wcat_b = (unsigned short*)alloc((size_t)5632 * H_ * 2); // [Wa; W_hh(perm); out_w]
    unsigned short* Wih1_b = (unsigned short*)alloc((size_t)G4 * H_ * 2);   // W_ih[:, :H] perm
    unsigned short* Wih2_b = (unsigned short*)alloc((size_t)G4 * H_ * 2);   // W_ih[:, H:] perm
    unsigned short* Uaw_b  = (unsigned short*)alloc((size_t)H_ * H_ * 2);
    unsigned short* emb_b  = (unsigned short*)alloc((size_t)V_ * H_ * 2);
    unsigned short* hb     = (unsigned short*)alloc((size_t)B_ * H_ * 2);
    unsigned short* ctxb   = (unsigned short*)alloc((size_t)B_ * H_ * 2);
    float* Pemb  = (float*)alloc((size_t)V_ * G4 * 4);
    float* bsumP = (float*)alloc((size_t)G4 * 4);
    int*   toks  = (int*)alloc((size_t)T_ * B_ * 4);
    float* cbuf  = (float*)alloc((size_t)B_ * H_ * 4);
    float* qbuf  = (float*)alloc((size_t)B_ * H_ * 4);
    float* gates = (float*)alloc((size_t)B_ * G4 * 4);
    float* lgbuf = (float*)alloc((size_t)B_ * V_ * 4);
    float* es_g  = (float*)alloc((size_t)B_ * S_ * 4);
    float* pctx  = (float*)alloc((size_t)B_ * 16 * H_ * 4);
    if ((size_t)(w - (char*)d_ws) > ws_size) return;

    auto cvt = [&](const float* src, unsigned short* dst, size_t n) {
        int n4 = (int)(n / 4);
        f32_to_bf16_x4<<<(n4 + 255) / 256, 256, 0, stream>>>((const float4*)src, (ushort4*)dst, n4);
    };

    // precompute
    cvt(enc, encb, NKP);
    cvt(Ua_w, Uaw_b, (size_t)H_ * H_);
    cvt(emb, emb_b, (size_t)V_ * H_);
    cvt(h0, hb, (size_t)B_ * H_);
    cvt_gather<<<1024, 256, 0, stream>>>(Wa_w, H_, 0, Wcat_b, 0);
    cvt_gather<<<4096, 256, 0, stream>>>(W_hh, H_, 0, Wcat_b + (size_t)1024 * H_, 1);
    cvt_gather<<<512, 256, 0, stream>>>(out_w, H_, 0, Wcat_b + (size_t)5120 * H_, 0);
    cvt_gather<<<4096, 256, 0, stream>>>(W_ih, 2 * H_, 0, Wih1_b, 1);
    cvt_gather<<<4096, 256, 0, stream>>>(W_ih, 2 * H_, H_, Wih2_b, 1);
    build_toks<<<(T_ * B_ + 255) / 256, 256, 0, stream>>>(targ, toks);
    build_bsum<<<(G4 + 255) / 256, 256, 0, stream>>>(b_ih, b_hh, bsumP);
    hipMemcpyAsync(cbuf, c0, (size_t)B_ * H_ * 4, hipMemcpyDeviceToDevice, stream);

    // keys_proj: kp = encb @ Ua_w^T + Ua_b (bf16 out)
    gemm_mf<1><<<dim3((B_ * S_) / 64, H_ / 64), 256, 0, stream>>>(
        encb, Uaw_b, H_, H_, H_, nullptr, kp, Ua_b);
    // Pemb (permuted): emb @ W_ih[:, :H](perm)^T + bsumP
    gemm_mf<0><<<dim3(V_ / 64, G4 / 64), 256, 0, stream>>>(
        emb_b, Wih1_b, H_, H_, G4, Pemb, nullptr, bsumP);

    // sequential decode: 4 launches per step
    for (int t = 0; t < T_; ++t) {
        gemm_n32<2><<<dim3(2, 176), 256, 0, stream>>>(
            hb, Wcat_b, H_, H_, 0, gates, nullptr, Wa_b,
            Pemb, toks + t * B_, qbuf, lgbuf, out_b, 0);
        attn_e<<<dim3(B_, 16), 256, 0, stream>>>(
            kp, qbuf, Va_w, encb, es_g, pctx, lgbuf, lp, t);
        attn_comb<<<dim3(B_, 2), 256, 0, stream>>>(es_g, pctx, ctxb, attn, t);
        gemm_n32<4><<<dim3(2, 128), 256, 0, stream>>>(
            ctxb, Wih2_b, H_, H_, 0, gates, hb, nullptr,
            nullptr, nullptr, cbuf, hid, nullptr, t == T_ - 1);
    }
    // logits + lsm for final step
    gemm_n32<0><<<dim3(2, 16), 256, 0, stream>>>(
        hb, Wcat_b + (size_t)5120 * H_, H_, H_, V_, lgbuf, nullptr, out_b,
        nullptr, nullptr, nullptr, nullptr, nullptr, 0);
    lsm_kernel<<<B_, 256, 0, stream>>>(lgbuf, lp, T_ - 1);
}

// Round 9
// 6220.263 us; speedup vs baseline: 6.7471x; 1.0074x over previous
//
#include <hip/hip_runtime.h>

#define B_ 128
#define S_ 256
#define H_ 1024
#define V_ 512
#define T_ 128
#define G4 4096

typedef __attribute__((ext_vector_type(8))) short bf16x8;
typedef __attribute__((ext_vector_type(4))) float f32x4;

// ---------- helpers ----------
__device__ __forceinline__ float bf2f(unsigned short x) {
    unsigned int u = ((unsigned int)x) << 16;
    return __builtin_bit_cast(float, u);
}
__device__ __forceinline__ unsigned short f2b(float f) {
    unsigned int u = __builtin_bit_cast(unsigned int, f);
    u = u + 0x7fffu + ((u >> 16) & 1u);
    return (unsigned short)(u >> 16);
}
__device__ __forceinline__ float ftanh(float x) {
    float e = __expf(2.f * x);
    return 1.f - 2.f * __builtin_amdgcn_rcpf(e + 1.f);
}
__device__ __forceinline__ float fsigm(float x) {
    return __builtin_amdgcn_rcpf(1.f + __expf(-x));
}
__device__ __forceinline__ void gll16(const void* g, void* l) {
    __builtin_amdgcn_global_load_lds(
        (const __attribute__((address_space(1))) unsigned int*)g,
        (__attribute__((address_space(3))) unsigned int*)l, 16, 0, 0);
}

// ---------- small precompute kernels ----------
__global__ void f32_to_bf16_x4(const float4* __restrict__ in, ushort4* __restrict__ out, int n4) {
    int i = blockIdx.x * 256 + threadIdx.x;
    if (i < n4) {
        float4 v = in[i];
        ushort4 o;
        o.x = f2b(v.x); o.y = f2b(v.y); o.z = f2b(v.z); o.w = f2b(v.w);
        out[i] = o;
    }
}

__global__ void cvt_gather(const float* __restrict__ src, int src_ld, int coff,
                           unsigned short* __restrict__ dst, int perm) {
    int i = blockIdx.x * 256 + threadIdx.x;
    int r = i >> 8;
    int c = (i & 255) * 4;
    int sr = perm ? (((r & 3) << 10) + (r >> 2)) : r;
    float4 v = *reinterpret_cast<const float4*>(src + (size_t)sr * src_ld + coff + c);
    ushort4 o;
    o.x = f2b(v.x); o.y = f2b(v.y); o.z = f2b(v.z); o.w = f2b(v.w);
    *reinterpret_cast<ushort4*>(dst + (size_t)r * 1024 + c) = o;
}

__global__ void build_toks(const int* __restrict__ target, int* __restrict__ toks) {
    int idx = blockIdx.x * 256 + threadIdx.x;
    if (idx < T_ * B_) {
        int t = idx / B_, b = idx % B_;
        toks[idx] = (t == 0) ? 0 : target[b * T_ + t - 1];
    }
}

__global__ void build_bsum(const float* __restrict__ b_ih, const float* __restrict__ b_hh,
                           float* __restrict__ bsum) {
    int j = blockIdx.x * 256 + threadIdx.x;
    if (j < G4) {
        int pj = ((j & 3) << 10) + (j >> 2);
        bsum[j] = b_ih[pj] + b_hh[pj];
    }
}

// ---------- 64x64-tile bf16 MFMA GEMM (precompute only), BK=128, depth-2 counted vmcnt ----------
template<int MODE>
__global__ __launch_bounds__(256) void gemm_mf(
    const unsigned short* __restrict__ A,
    const unsigned short* __restrict__ Bw,
    int K, int ldb, int ldc,
    float* __restrict__ C, unsigned short* __restrict__ Cb,
    const float* __restrict__ bias)
{
    __shared__ unsigned short As[2 * 8192];
    __shared__ unsigned short Bs[2 * 8192];
    const int tid = threadIdx.x;
    const int lane = tid & 63;
    const int wv = tid >> 6;
    const int m0 = blockIdx.x * 64;
    const int n0 = blockIdx.y * 64;

    const unsigned short* ga[4];
    const unsigned short* gb[4];
    #pragma unroll
    for (int j = 0; j < 4; ++j) {
        int ci = tid + 256 * j;
        int row = ci >> 4;
        int src = (ci & 15) ^ (row & 7);
        ga[j] = A + (size_t)(m0 + row) * K + src * 8;
        gb[j] = Bw + (size_t)(n0 + row) * ldb + src * 8;
    }

    f32x4 acc[2][2] = {};
    const int r0 = (wv >> 1) * 32;
    const int cq0 = (wv & 1) * 32;
    const int fr = lane & 15;
    const int kg = lane >> 4;

    auto stage = [&](int k0, int p) {
        #pragma unroll
        for (int j = 0; j < 4; ++j) {
            gll16(ga[j] + k0, As + p * 8192 + j * 2048 + wv * 512);
            gll16(gb[j] + k0, Bs + p * 8192 + j * 2048 + wv * 512);
        }
    };

    stage(0, 0);
    stage(128, 1);
    int p = 0;
    for (int k0 = 0; k0 < K; k0 += 128) {
        if (k0 + 128 < K) {
            asm volatile("s_waitcnt vmcnt(8)" ::: "memory");
        } else {
            asm volatile("s_waitcnt vmcnt(0)" ::: "memory");
        }
        __builtin_amdgcn_sched_barrier(0);
        __builtin_amdgcn_s_barrier();
        __builtin_amdgcn_sched_barrier(0);
        const unsigned short* Ab = As + p * 8192;
        const unsigned short* Bb = Bs + p * 8192;
        bf16x8 af[2][4], bfr[2][4];
        #pragma unroll
        for (int f = 0; f < 2; ++f)
            #pragma unroll
            for (int kh = 0; kh < 4; ++kh) {
                int ra = r0 + f * 16 + fr;
                af[f][kh] = *(const bf16x8*)&Ab[ra * 128 + (((kh * 4 + kg) ^ (ra & 7)) << 3)];
                int rb = cq0 + f * 16 + fr;
                bfr[f][kh] = *(const bf16x8*)&Bb[rb * 128 + (((kh * 4 + kg) ^ (rb & 7)) << 3)];
            }
        asm volatile("s_waitcnt lgkmcnt(0)" ::: "memory");
        __builtin_amdgcn_sched_barrier(0);
        __builtin_amdgcn_s_barrier();
        __builtin_amdgcn_sched_barrier(0);
        if (k0 + 256 < K) stage(k0 + 256, p);
        __builtin_amdgcn_s_setprio(1);
        #pragma unroll
        for (int f = 0; f < 2; ++f)
            #pragma unroll
            for (int g = 0; g < 2; ++g)
                #pragma unroll
                for (int kh = 0; kh < 4; ++kh)
                    acc[f][g] = __builtin_amdgcn_mfma_f32_16x16x32_bf16(
                        af[f][kh], bfr[g][kh], acc[f][g], 0, 0, 0);
        __builtin_amdgcn_s_setprio(0);
        p ^= 1;
    }

    const int erow = (lane >> 4) * 4;
    const int ecol = lane & 15;
    #pragma unroll
    for (int f = 0; f < 2; ++f) {
        #pragma unroll
        for (int g = 0; g < 2; ++g) {
            #pragma unroll
            for (int r = 0; r < 4; ++r) {
                int row = m0 + r0 + f * 16 + erow + r;
                int col = n0 + cq0 + g * 16 + ecol;
                float v = acc[f][g][r] + bias[col];
                if (MODE == 0) C[(size_t)row * ldc + col] = v;
                else Cb[(size_t)row * ldc + col] = f2b(v);
            }
        }
    }
}

// ---------- 64x32-tile bf16 MFMA GEMM, BK=128, DEPTH-3 pipeline (per-step GEMMs) ----------
// MODE 0: C = v + bias[col]
// MODE 2: col<1024 -> Cq=q(+bias); col<5120 -> gates(+Pemb[tok]); else logits(t-1)+bias2
// MODE 4: gates-acc + fused LSTM pointwise epilogue
// K must be >= 384 and a multiple of 128 (K = 1024 for all call sites).
template<int MODE>
__global__ __launch_bounds__(256) void gemm_n32(
    const unsigned short* __restrict__ A,
    const unsigned short* __restrict__ Bw,
    int K, int ldb, int ldc,
    float* __restrict__ C, unsigned short* __restrict__ Cb,
    const float* __restrict__ bias,
    const float* __restrict__ Pemb,
    const int* __restrict__ toks,
    float* __restrict__ Cq,
    float* __restrict__ Lg,
    const float* __restrict__ bias2,
    int flag)
{
    __shared__ unsigned short As[3 * 8192];   // 64 x 128 x 3 buffers
    __shared__ unsigned short Bs[3 * 4096];   // 32 x 128 x 3 buffers
    const int tid = threadIdx.x;
    const int lane = tid & 63;
    const int wv = tid >> 6;
    const int m0 = blockIdx.x * 64;
    const int n0 = blockIdx.y * 32;

    const unsigned short* ga[4];
    const unsigned short* gb[2];
    #pragma unroll
    for (int j = 0; j < 4; ++j) {
        int ci = tid + 256 * j;
        int row = ci >> 4;
        int src = (ci & 15) ^ (row & 7);
        ga[j] = A + (size_t)(m0 + row) * K + src * 8;
    }
    #pragma unroll
    for (int j = 0; j < 2; ++j) {
        int ci = tid + 256 * j;
        int row = ci >> 4;
        int src = (ci & 15) ^ (row & 7);
        gb[j] = Bw + (size_t)(n0 + row) * ldb + src * 8;
    }

    f32x4 acc[2] = {};
    const int r0 = (wv >> 1) * 32;
    const int c0 = (wv & 1) * 16;
    const int fr = lane & 15;
    const int kg = lane >> 4;

    auto stage = [&](int k0, int p) {
        #pragma unroll
        for (int j = 0; j < 4; ++j)
            gll16(ga[j] + k0, As + p * 8192 + j * 2048 + wv * 512);
        #pragma unroll
        for (int j = 0; j < 2; ++j)
            gll16(gb[j] + k0, Bs + p * 4096 + j * 2048 + wv * 512);
    };

    stage(0, 0);
    stage(128, 1);
    stage(256, 2);
    int p = 0;
    for (int k0 = 0; k0 < K; k0 += 128) {
        // wait for the current tile: 6 loads per in-flight future tile stay outstanding
        if (k0 + 256 < K) {
            asm volatile("s_waitcnt vmcnt(12)" ::: "memory");
        } else if (k0 + 128 < K) {
            asm volatile("s_waitcnt vmcnt(6)" ::: "memory");
        } else {
            asm volatile("s_waitcnt vmcnt(0)" ::: "memory");
        }
        __builtin_amdgcn_sched_barrier(0);
        __builtin_amdgcn_s_barrier();
        __builtin_amdgcn_sched_barrier(0);
        const unsigned short* Ab = As + p * 8192;
        const unsigned short* Bb = Bs + p * 4096;
        bf16x8 af[2][4], bfr[4];
        #pragma unroll
        for (int kh = 0; kh < 4; ++kh) {
            #pragma unroll
            for (int f = 0; f < 2; ++f) {
                int ra = r0 + f * 16 + fr;
                af[f][kh] = *(const bf16x8*)&Ab[ra * 128 + (((kh * 4 + kg) ^ (ra & 7)) << 3)];
            }
            int rb = c0 + fr;
            bfr[kh] = *(const bf16x8*)&Bb[rb * 128 + (((kh * 4 + kg) ^ (rb & 7)) << 3)];
        }
        asm volatile("s_waitcnt lgkmcnt(0)" ::: "memory");
        __builtin_amdgcn_sched_barrier(0);
        __builtin_amdgcn_s_barrier();
        __builtin_amdgcn_sched_barrier(0);
        if (k0 + 384 < K) stage(k0 + 384, p);   // buf p fully consumed; reuse for tile i+3
        __builtin_amdgcn_s_setprio(1);
        #pragma unroll
        for (int f = 0; f < 2; ++f)
            #pragma unroll
            for (int kh = 0; kh < 4; ++kh)
                acc[f] = __builtin_amdgcn_mfma_f32_16x16x32_bf16(
                    af[f][kh], bfr[kh], acc[f], 0, 0, 0);
        __builtin_amdgcn_s_setprio(0);
        p = (p == 2) ? 0 : p + 1;
    }

    const int erow = (lane >> 4) * 4;
    const int ecol = lane & 15;

    if constexpr (MODE == 4) {
        __shared__ float Lt[64 * 32];
        __syncthreads();
        #pragma unroll
        for (int f = 0; f < 2; ++f)
            #pragma unroll
            for (int r = 0; r < 4; ++r)
                Lt[(r0 + f * 16 + erow + r) * 32 + c0 + ecol] = acc[f][r];
        __syncthreads();
        #pragma unroll
        for (int i = 0; i < 2; ++i) {
            int pi = tid + 256 * i;
            int r = pi >> 3, u = pi & 7;
            int b = m0 + r;
            int hh = (n0 >> 2) + u;
            f32x4 gv = *reinterpret_cast<const f32x4*>(&Lt[r * 32 + u * 4]);
            const float* gp = C + (size_t)b * G4 + n0 + u * 4;
            float iv = gv[0] + gp[0];
            float fv = gv[1] + gp[1];
            float gg = gv[2] + gp[2];
            float ov = gv[3] + gp[3];
            int ci = b * H_ + hh;
            float cn = fsigm(fv) * Cq[ci] + fsigm(iv) * ftanh(gg);
            float hn = fsigm(ov) * ftanh(cn);
            Cq[ci] = cn;
            Cb[ci] = f2b(hn);
            if (flag) Lg[ci] = hn;
        }
    } else {
        #pragma unroll
        for (int f = 0; f < 2; ++f) {
            #pragma unroll
            for (int r = 0; r < 4; ++r) {
                int row = m0 + r0 + f * 16 + erow + r;
                int col = n0 + c0 + ecol;
                float v = acc[f][r];
                if (MODE == 0) {
                    C[(size_t)row * ldc + col] = v + bias[col];
                } else {  // MODE 2
                    if (col < H_) {
                        Cq[(size_t)row * H_ + col] = v + bias[col];
                    } else if (col < 5120) {
                        int cg = col - H_;
                        C[(size_t)row * G4 + cg] = v + Pemb[(size_t)toks[row] * G4 + cg];
                    } else {
                        int cl = col - 5120;
                        Lg[(size_t)row * V_ + cl] = v + bias2[cl];
                    }
                }
            }
        }
    }
}

// ---------- attention energies + raw-exp partial context (+ lsm of t-1), grid (B,16) x 256 ----------
// Energies are bounded: |e| <= sum|Va| ~ 25 -> raw exp is overflow-safe in f32.
__global__ __launch_bounds__(256) void attn_e(
    const unsigned short* __restrict__ kp,   // [B*S, H] bf16
    const float* __restrict__ q,             // [B, H]
    const float* __restrict__ Va,            // [H]
    const unsigned short* __restrict__ encb, // [B*S, H] bf16
    float* __restrict__ es_g,                // [B, S]
    unsigned short* __restrict__ pctx,       // [B, 16, H] bf16 raw-exp-weighted partial ctx
    const float* __restrict__ lg,            // [B, V] logits t-1
    float* __restrict__ lp,                  // [B,T,V]
    int t)
{
    const int b = blockIdx.x;
    const int sh = blockIdx.y;  // s-chunk of 16
    const int tid = threadIdx.x;
    const int lane = tid & 63;
    const int wv = tid >> 6;    // 0..3
    __shared__ float qs[H_];
    __shared__ float vas[H_];
    __shared__ float pe[16];
    __shared__ float redm[4], reds[4];

    *reinterpret_cast<float4*>(&qs[tid * 4]) =
        *reinterpret_cast<const float4*>(&q[(size_t)b * H_ + tid * 4]);
    *reinterpret_cast<float4*>(&vas[tid * 4]) =
        *reinterpret_cast<const float4*>(&Va[tid * 4]);

    // ---- log-softmax(t-1), sh==0 blocks only; barriers unconditional ----
    const bool doL = (t > 0) && (sh == 0);
    float a0 = doL ? lg[(size_t)b * V_ + tid] : -3.4e38f;
    float a1 = doL ? lg[(size_t)b * V_ + 256 + tid] : -3.4e38f;
    float mx = fmaxf(a0, a1);
    #pragma unroll
    for (int off = 32; off; off >>= 1) mx = fmaxf(mx, __shfl_xor(mx, off));
    if (lane == 0) redm[wv] = mx;
    __syncthreads();                         // also publishes qs/vas
    mx = fmaxf(fmaxf(redm[0], redm[1]), fmaxf(redm[2], redm[3]));
    float sm = doL ? (__expf(a0 - mx) + __expf(a1 - mx)) : 0.f;
    #pragma unroll
    for (int off = 32; off; off >>= 1) sm += __shfl_xor(sm, off);
    if (lane == 0) reds[wv] = sm;
    __syncthreads();
    if (doL) {
        sm = reds[0] + reds[1] + reds[2] + reds[3];
        float lse = mx + __logf(sm);
        size_t off = ((size_t)b * T_ + (t - 1)) * V_;
        lp[off + tid] = a0 - lse;
        lp[off + tid + 256] = a1 - lse;
    }

    // ---- energies: wave wv handles s_loc = wv*4 + 0..3 ----
    #pragma unroll
    for (int si = 0; si < 4; ++si) {
        int s_loc = wv * 4 + si;
        const unsigned short* kr = kp + (size_t)(b * S_ + sh * 16 + s_loc) * H_;
        float acc = 0.f;
        #pragma unroll
        for (int it = 0; it < 4; ++it) {
            int h4 = lane * 4 + it * 256;
            ushort4 u = *reinterpret_cast<const ushort4*>(kr + h4);
            acc += vas[h4 + 0] * ftanh(qs[h4 + 0] + bf2f(u.x));
            acc += vas[h4 + 1] * ftanh(qs[h4 + 1] + bf2f(u.y));
            acc += vas[h4 + 2] * ftanh(qs[h4 + 2] + bf2f(u.z));
            acc += vas[h4 + 3] * ftanh(qs[h4 + 3] + bf2f(u.w));
        }
        #pragma unroll
        for (int off = 32; off; off >>= 1) acc += __shfl_down(acc, off);
        if (lane == 0) {
            pe[s_loc] = __expf(acc);
            es_g[(size_t)b * S_ + sh * 16 + s_loc] = acc;
        }
    }
    __syncthreads();

    // ---- raw-exp-weighted partial context (bf16 out) ----
    const int c0 = tid * 4;
    float ax = 0.f, ay = 0.f, az = 0.f, aw = 0.f;
    #pragma unroll
    for (int sl = 0; sl < 16; ++sl) {
        ushort4 u = *reinterpret_cast<const ushort4*>(
            &encb[(size_t)(b * S_ + sh * 16 + sl) * H_ + c0]);
        float w = pe[sl];
        ax += w * bf2f(u.x);
        ay += w * bf2f(u.y);
        az += w * bf2f(u.z);
        aw += w * bf2f(u.w);
    }
    ushort4 o4;
    o4.x = f2b(ax); o4.y = f2b(ay); o4.z = f2b(az); o4.w = f2b(aw);
    *reinterpret_cast<ushort4*>(&pctx[((size_t)b * 16 + sh) * H_ + c0]) = o4;
}

// ---------- combine: Z-sum + attn-weight store + ctx finalize, grid (B,2) x 256 ----------
__global__ __launch_bounds__(256) void attn_comb(
    const float* __restrict__ es_g,          // [B, S]
    const unsigned short* __restrict__ pctx, // [B, 16, H] bf16
    unsigned short* __restrict__ ctxb,       // [B, H] bf16
    float* __restrict__ attnOut,             // [B,T,S]
    int t)
{
    const int b = blockIdx.x;
    const int hh = blockIdx.y;  // h-half (512 cols)
    const int tid = threadIdx.x;
    const int lane = tid & 63;
    const int wv = tid >> 6;
    __shared__ float reds[4];

    float ex = __expf(es_g[(size_t)b * S_ + tid]);
    float sm = ex;
    #pragma unroll
    for (int off = 32; off; off >>= 1) sm += __shfl_xor(sm, off);
    if (lane == 0) reds[wv] = sm;
    __syncthreads();
    sm = reds[0] + reds[1] + reds[2] + reds[3];
    float rZ = __builtin_amdgcn_rcpf(sm);
    if (hh == 0) attnOut[((size_t)(b * T_ + t)) * S_ + tid] = ex * rZ;

    const int c0 = hh * 512 + tid * 2;
    float a0 = 0.f, a1 = 0.f;
    #pragma unroll
    for (int blk = 0; blk < 16; ++blk) {
        ushort2 pv = *reinterpret_cast<const ushort2*>(
            &pctx[((size_t)b * 16 + blk) * H_ + c0]);
        a0 += bf2f(pv.x); a1 += bf2f(pv.y);
    }
    ushort2 o; o.x = f2b(a0 * rZ); o.y = f2b(a1 * rZ);
    *reinterpret_cast<ushort2*>(&ctxb[(size_t)b * H_ + c0]) = o;
}

// ---------- standalone log-softmax (final step only) ----------
__global__ __launch_bounds__(256) void lsm_kernel(
    const float* __restrict__ lg, float* __restrict__ lp, int t)
{
    int b = blockIdx.x, tid = threadIdx.x;
    int lane = tid & 63, wv = tid >> 6;
    __shared__ float red[4];
    float a0 = lg[(size_t)b * V_ + tid];
    float a1 = lg[(size_t)b * V_ + 256 + tid];
    float mx = fmaxf(a0, a1);
    #pragma unroll
    for (int off = 32; off; off >>= 1) mx = fmaxf(mx, __shfl_xor(mx, off));
    if (lane == 0) red[wv] = mx;
    __syncthreads();
    mx = fmaxf(fmaxf(red[0], red[1]), fmaxf(red[2], red[3]));
    float sm = __expf(a0 - mx) + __expf(a1 - mx);
    #pragma unroll
    for (int off = 32; off; off >>= 1) sm += __shfl_xor(sm, off);
    __syncthreads();
    if (lane == 0) red[wv] = sm;
    __syncthreads();
    sm = red[0] + red[1] + red[2] + red[3];
    float lse = mx + __logf(sm);
    size_t off = ((size_t)b * T_ + t) * V_;
    lp[off + tid] = a0 - lse;
    lp[off + tid + 256] = a1 - lse;
}

// ---------- launch ----------
extern "C" void kernel_launch(void* const* d_in, const int* in_sizes, int n_in,
                              void* d_out, int out_size, void* d_ws, size_t ws_size,
                              hipStream_t stream) {
    const float* enc   = (const float*)d_in[0];
    const float* h0    = (const float*)d_in[1];
    const float* c0    = (const float*)d_in[2];
    const int*   targ  = (const int*)d_in[3];
    const float* emb   = (const float*)d_in[5];
    const float* Wa_w  = (const float*)d_in[6];
    const float* Wa_b  = (const float*)d_in[7];
    const float* Ua_w  = (const float*)d_in[8];
    const float* Ua_b  = (const float*)d_in[9];
    const float* Va_w  = (const float*)d_in[10];
    const float* W_ih  = (const float*)d_in[12];
    const float* W_hh  = (const float*)d_in[13];
    const float* b_ih  = (const float*)d_in[14];
    const float* b_hh  = (const float*)d_in[15];
    const float* out_w = (const float*)d_in[16];
    const float* out_b = (const float*)d_in[17];

    float* out  = (float*)d_out;
    float* lp   = out;                          // [B,T,V]
    float* hid  = out + (size_t)B_ * T_ * V_;   // [1,B,H]
    float* attn = hid + (size_t)B_ * H_;        // [B,T,S]

    char* w = (char*)d_ws;
    auto alloc = [&](size_t bytes) {
        char* p = w;
        w += (bytes + 255) & ~(size_t)255;
        return p;
    };
    const size_t NKP = (size_t)B_ * S_ * H_;
    unsigned short* kp     = (unsigned short*)alloc(NKP * 2);
    unsigned short* encb   = (unsigned short*)alloc(NKP * 2);
    unsigned short* Wcat_b = (unsigned short*)alloc((size_t)5632 * H_ * 2); // [Wa; W_hh(perm); out_w]
    unsigned short* Wih1_b = (unsigned short*)alloc((size_t)G4 * H_ * 2);   // W_ih[:, :H] perm
    unsigned short* Wih2_b = (unsigned short*)alloc((size_t)G4 * H_ * 2);   // W_ih[:, H:] perm
    unsigned short* Uaw_b  = (unsigned short*)alloc((size_t)H_ * H_ * 2);
    unsigned short* emb_b  = (unsigned short*)alloc((size_t)V_ * H_ * 2);
    unsigned short* hb     = (unsigned short*)alloc((size_t)B_ * H_ * 2);
    unsigned short* ctxb   = (unsigned short*)alloc((size_t)B_ * H_ * 2);
    float* Pemb  = (float*)alloc((size_t)V_ * G4 * 4);
    float* bsumP = (float*)alloc((size_t)G4 * 4);
    int*   toks  = (int*)alloc((size_t)T_ * B_ * 4);
    float* cbuf  = (float*)alloc((size_t)B_ * H_ * 4);
    float* qbuf  = (float*)alloc((size_t)B_ * H_ * 4);
    float* gates = (float*)alloc((size_t)B_ * G4 * 4);
    float* lgbuf = (float*)alloc((size_t)B_ * V_ * 4);
    float* es_g  = (float*)alloc((size_t)B_ * S_ * 4);
    unsigned short* pctx = (unsigned short*)alloc((size_t)B_ * 16 * H_ * 2);
    if ((size_t)(w - (char*)d_ws) > ws_size) return;

    auto cvt = [&](const float* src, unsigned short* dst, size_t n) {
        int n4 = (int)(n / 4);
        f32_to_bf16_x4<<<(n4 + 255) / 256, 256, 0, stream>>>((const float4*)src, (ushort4*)dst, n4);
    };

    // precompute
    cvt(enc, encb, NKP);
    cvt(Ua_w, Uaw_b, (size_t)H_ * H_);
    cvt(emb, emb_b, (size_t)V_ * H_);
    cvt(h0, hb, (size_t)B_ * H_);
    cvt_gather<<<1024, 256, 0, stream>>>(Wa_w, H_, 0, Wcat_b, 0);
    cvt_gather<<<4096, 256, 0, stream>>>(W_hh, H_, 0, Wcat_b + (size_t)1024 * H_, 1);
    cvt_gather<<<512, 256, 0, stream>>>(out_w, H_, 0, Wcat_b + (size_t)5120 * H_, 0);
    cvt_gather<<<4096, 256, 0, stream>>>(W_ih, 2 * H_, 0, Wih1_b, 1);
    cvt_gather<<<4096, 256, 0, stream>>>(W_ih, 2 * H_, H_, Wih2_b, 1);
    build_toks<<<(T_ * B_ + 255) / 256, 256, 0, stream>>>(targ, toks);
    build_bsum<<<(G4 + 255) / 256, 256, 0, stream>>>(b_ih, b_hh, bsumP);
    hipMemcpyAsync(cbuf, c0, (size_t)B_ * H_ * 4, hipMemcpyDeviceToDevice, stream);

    // keys_proj: kp = encb @ Ua_w^T + Ua_b (bf16 out)
    gemm_mf<1><<<dim3((B_ * S_) / 64, H_ / 64), 256, 0, stream>>>(
        encb, Uaw_b, H_, H_, H_, nullptr, kp, Ua_b);
    // Pemb (permuted): emb @ W_ih[:, :H](perm)^T + bsumP
    gemm_mf<0><<<dim3(V_ / 64, G4 / 64), 256, 0, stream>>>(
        emb_b, Wih1_b, H_, H_, G4, Pemb, nullptr, bsumP);

    // sequential decode: 4 launches per step
    for (int t = 0; t < T_; ++t) {
        gemm_n32<2><<<dim3(2, 176), 256, 0, stream>>>(
            hb, Wcat_b, H_, H_, 0, gates, nullptr, Wa_b,
            Pemb, toks + t * B_, qbuf, lgbuf, out_b, 0);
        attn_e<<<dim3(B_, 16), 256, 0, stream>>>(
            kp, qbuf, Va_w, encb, es_g, pctx, lgbuf, lp, t);
        attn_comb<<<dim3(B_, 2), 256, 0, stream>>>(es_g, pctx, ctxb, attn, t);
        gemm_n32<4><<<dim3(2, 128), 256, 0, stream>>>(
            ctxb, Wih2_b, H_, H_, 0, gates, hb, nullptr,
            nullptr, nullptr, cbuf, hid, nullptr, t == T_ - 1);
    }
    // logits + lsm for final step
    gemm_n32<0><<<dim3(2, 16), 256, 0, stream>>>(
        hb, Wcat_b + (size_t)5120 * H_, H_, H_, V_, lgbuf, nullptr, out_b,
        nullptr, nullptr, nullptr, nullptr, nullptr, 0);
    lsm_kernel<<<B_, 256, 0, stream>>>(lgbuf, lp, T_ - 1);
}